// Round 3
// baseline (232.343 us; speedup 1.0000x reference)
//
#include <hip/hip_runtime.h>
#include <stdint.h>
#include <stddef.h>

#define DEVI __device__ __forceinline__

typedef __bf16 bf16x8 __attribute__((ext_vector_type(8)));
typedef float  f32x4  __attribute__((ext_vector_type(4)));
typedef float  f32x16 __attribute__((ext_vector_type(16)));
typedef unsigned short u16;
typedef uint32_t u32;
typedef u16 u16x8 __attribute__((ext_vector_type(8)));
typedef u16 u16x4 __attribute__((ext_vector_type(4)));
typedef u32 u32x2 __attribute__((ext_vector_type(2)));
typedef u32 u32x4 __attribute__((ext_vector_type(4)));

typedef __attribute__((address_space(1))) void as1_void;
typedef __attribute__((address_space(3))) void as3_void;

static constexpr float SC = 0.18033688011112042f;  // (1/8) * log2(e)

DEVI u16 f2bf(float f) {
  uint32_t u = __builtin_bit_cast(uint32_t, f);
  u += 0x7fffu + ((u >> 16) & 1u);
  return (u16)(u >> 16);
}

DEVI void gload_lds16(const void* g, void* l) {
  __builtin_amdgcn_global_load_lds((as1_void*)(void*)g, (as3_void*)l, 16, 0, 0);
}

#if __has_builtin(__builtin_amdgcn_exp2f)
DEVI float fast_exp2(float x) { return __builtin_amdgcn_exp2f(x); }
#else
DEVI float fast_exp2(float x) { return exp2f(x); }
#endif

DEVI u32 cvtpk(float lo, float hi) {
  u32 r;
  asm("v_cvt_pk_bf16_f32 %0, %1, %2" : "=v"(r) : "v"(lo), "v"(hi));
  return r;
}
DEVI void plswap(u32& a, u32& b) {
  asm("v_permlane32_swap_b32 %0, %1" : "+v"(a), "+v"(b));
}

// ---------------- elementwise fp32 -> bf16 ----------------
__global__ __launch_bounds__(256) void k_cvt(const float* __restrict__ in,
                                             u16* __restrict__ out, int n) {
  int i = (blockIdx.x * 256 + threadIdx.x) * 4;
  if (i >= n) return;
  const float4 v = *(const float4*)(in + i);
  u16x4 o = { f2bf(v.x), f2bf(v.y), f2bf(v.z), f2bf(v.w) };
  *(u16x4*)(out + i) = o;
}

// ------------- transpose + convert: in fp32 [R][C] -> out bf16 [C][R] -------------
__global__ __launch_bounds__(256) void k_tcvt(const float* __restrict__ in,
                                              u16* __restrict__ out, int R, int C) {
  __shared__ float tile[32][33];
  const int c0 = blockIdx.x * 32, r0 = blockIdx.y * 32;
  const int tx = threadIdx.x, ty = threadIdx.y;
#pragma unroll
  for (int i = ty; i < 32; i += 8)
    tile[i][tx] = in[(size_t)(r0 + i) * C + (c0 + tx)];
  __syncthreads();
#pragma unroll
  for (int i = ty; i < 32; i += 8)
    out[(size_t)(c0 + i) * R + (r0 + tx)] = f2bf(tile[tx][i]);
}

// ---------------- GEMM: C[M][N] = A[M][K] * Bt[N][K]^T  (bf16 in, fp32 acc) ----------------
// EPI 0: qkv epilogue (q,k bf16 [B,H,S,d]; v -> vT bf16 [B,H,d,S]; present fp32)
// EPI 1: proj epilogue (fp32 out + bias)
template <int EPI>
__global__ __launch_bounds__(256) void k_gemm(
    const u16* __restrict__ A, const u16* __restrict__ Bt,
    const float* __restrict__ bias,
    u16* __restrict__ wq, u16* __restrict__ wk, u16* __restrict__ vt,
    float* __restrict__ pk, float* __restrict__ pv, float* __restrict__ of) {
  constexpr int K = 1024;
  __shared__ __align__(16) u16 Ash[128 * 32];
  __shared__ __align__(16) u16 Bsh[128 * 32];
  const int tid = threadIdx.x;
  const int lane = tid & 63, wid = tid >> 6;
  const int wm = wid >> 1, wn = wid & 1;
  const int lr = lane & 15, lg = lane >> 4;
  const int m0 = blockIdx.y * 128, n0 = blockIdx.x * 128;

  const int c = wid * 64 + lane;  // 16B chunk id, 0..255
  const u16* Ag1 = A + (size_t)(m0 + (c >> 2)) * K + (c & 3) * 8;
  const u16* Ag2 = A + (size_t)(m0 + 64 + (c >> 2)) * K + (c & 3) * 8;
  const u16* Bg1 = Bt + (size_t)(n0 + (c >> 2)) * K + (c & 3) * 8;
  const u16* Bg2 = Bt + (size_t)(n0 + 64 + (c >> 2)) * K + (c & 3) * 8;
  u16* Ad1 = Ash + wid * 512;
  u16* Ad2 = Ash + 2048 + wid * 512;
  u16* Bd1 = Bsh + wid * 512;
  u16* Bd2 = Bsh + 2048 + wid * 512;

  f32x4 acc[4][4];
#pragma unroll
  for (int i = 0; i < 4; ++i)
#pragma unroll
    for (int j = 0; j < 4; ++j) acc[i][j] = (f32x4)0.0f;

  for (int k0 = 0; k0 < K; k0 += 32) {
    gload_lds16(Ag1 + k0, Ad1);
    gload_lds16(Ag2 + k0, Ad2);
    gload_lds16(Bg1 + k0, Bd1);
    gload_lds16(Bg2 + k0, Bd2);
    __syncthreads();
    bf16x8 af[4], bfr[4];
#pragma unroll
    for (int f = 0; f < 4; ++f) {
      af[f]  = *(const bf16x8*)&Ash[(wm * 64 + f * 16 + lr) * 32 + lg * 8];
      bfr[f] = *(const bf16x8*)&Bsh[(wn * 64 + f * 16 + lr) * 32 + lg * 8];
    }
#pragma unroll
    for (int i = 0; i < 4; ++i)
#pragma unroll
      for (int j = 0; j < 4; ++j)
        acc[i][j] = __builtin_amdgcn_mfma_f32_16x16x32_bf16(af[i], bfr[j], acc[i][j], 0, 0, 0);
    __syncthreads();
  }

  if constexpr (EPI == 0) {
#pragma unroll
    for (int j = 0; j < 4; ++j) {
      const int n = n0 + wn * 64 + j * 16 + lr;
      const float bv = bias[n];
      const int sec = n >> 10;
      const int nn = n & 1023;
      const int h = nn >> 6, dd = nn & 63;
#pragma unroll
      for (int i = 0; i < 4; ++i) {
        const int mb = m0 + wm * 64 + i * 16 + lg * 4;
        const int bb = mb >> 11, ss = mb & 2047;
        const size_t ib = (size_t)(bb * 16 + h) * 131072 + (size_t)ss * 64 + dd;
        if (sec == 0) {
#pragma unroll
          for (int r = 0; r < 4; ++r)
            wq[ib + (size_t)r * 64] = f2bf(acc[i][j][r] + bv);
        } else if (sec == 1) {
#pragma unroll
          for (int r = 0; r < 4; ++r) {
            const float v = acc[i][j][r] + bv;
            wk[ib + (size_t)r * 64] = f2bf(v);
            pk[ib + (size_t)r * 64] = v;
          }
        } else {
          u16x4 vv;
#pragma unroll
          for (int r = 0; r < 4; ++r) {
            const float v = acc[i][j][r] + bv;
            pv[ib + (size_t)r * 64] = v;
            vv[r] = f2bf(v);
          }
          *(u16x4*)(vt + ((size_t)(bb * 16 + h) * 64 + dd) * 2048 + ss) = vv;
        }
      }
    }
  } else {
#pragma unroll
    for (int j = 0; j < 4; ++j) {
      const int n = n0 + wn * 64 + j * 16 + lr;
      const float bv = bias[n];
#pragma unroll
      for (int i = 0; i < 4; ++i) {
        const int mb = m0 + wm * 64 + i * 16 + lg * 4;
#pragma unroll
        for (int r = 0; r < 4; ++r)
          of[(size_t)(mb + r) * 1024 + n] = acc[i][j][r] + bv;
      }
    }
  }
}

// ---------------- causal flash attention, swapped-QK^T, KV-split ----------------
// 1024 blocks x 256 thr. Block = (bh = bid&31, pair = bid>>5).
// Waves 0,1 -> q-tile `pair` (32 rows); waves 2,3 -> q-tile `63-pair`.
// Each wave does half the tile's KV range with its own online-softmax partial;
// partials merge once via LDS (flash combine). 4096 waves = 4/SIMD.
__global__ __launch_bounds__(256, 4) void k_attn(const u16* __restrict__ Q,
                                                 const u16* __restrict__ Kp,
                                                 const u16* __restrict__ VT,
                                                 u16* __restrict__ AO) {
  __shared__ float Osl[2][32][64];
  __shared__ float Msl[2][64];
  __shared__ float Lsl[2][64];

  const int tid = threadIdx.x;
  const int lane = tid & 63, w = tid >> 6;
  const int l31 = lane & 31, hi = lane >> 5;
  const int s = w & 1, ti = w >> 1;
  const int bh = blockIdx.x & 31;          // bh%8 == bid%8 -> bh pinned per-XCD
  const int pair = blockIdx.x >> 5;        // 0..31
  const int b = bh >> 4, h = bh & 15;
  const size_t hb = (size_t)bh * (2048 * 64);

  const int qt = ti ? (63 - pair) : pair;
  const int qb = qt * 32;
  const int T = (qt >> 1) + 1;             // # of 64-wide KV tiles
  const int mid = (T + 1) >> 1;
  const int lo = s ? mid : 0;
  const int hiB = s ? T : mid;
  const int jtmax = T - 1;                 // diagonal tile index

  const u16* Kbase = Kp + hb + (size_t)l31 * 64 + hi * 8;
  const u16* Vbase = VT + hb + (size_t)l31 * 2048 + hi * 8;
  const u16* Qbase = Q  + hb + (size_t)l31 * 64 + hi * 8;

  const bf16x8 qf0 = *(const bf16x8*)(Qbase + (size_t)qb * 64);
  const bf16x8 qf1 = *(const bf16x8*)(Qbase + (size_t)qb * 64 + 16);
  const bf16x8 qf2 = *(const bf16x8*)(Qbase + (size_t)qb * 64 + 32);
  const bf16x8 qf3 = *(const bf16x8*)(Qbase + (size_t)qb * 64 + 48);

  f32x16 o0 = (f32x16)0.0f, o1 = (f32x16)0.0f;
  float mrun = -1e30f, lrun = 0.0f;

  bf16x8 kf[2][4];
#pragma unroll
  for (int ss = 0; ss < 2; ++ss)
#pragma unroll
    for (int c = 0; c < 4; ++c)
      kf[ss][c] = *(const bf16x8*)(Kbase + (size_t)(lo * 64 + ss * 32) * 64 + c * 16);

  for (int jt = lo; jt < hiB; ++jt) {
    // V^T fragments for this KV tile (used at the end -> latency hidden)
    bf16x8 vf[2][4];
#pragma unroll
    for (int mt = 0; mt < 2; ++mt)
#pragma unroll
      for (int c = 0; c < 4; ++c)
        vf[mt][c] = *(const bf16x8*)(Vbase + (size_t)(mt * 32) * 2048 + jt * 64 + c * 16);

    // S^T[kpos][q] = K . Q^T
    f32x16 s0 = (f32x16)0.0f, s1 = (f32x16)0.0f;
    s0 = __builtin_amdgcn_mfma_f32_32x32x16_bf16(kf[0][0], qf0, s0, 0, 0, 0);
    s1 = __builtin_amdgcn_mfma_f32_32x32x16_bf16(kf[1][0], qf0, s1, 0, 0, 0);
    s0 = __builtin_amdgcn_mfma_f32_32x32x16_bf16(kf[0][1], qf1, s0, 0, 0, 0);
    s1 = __builtin_amdgcn_mfma_f32_32x32x16_bf16(kf[1][1], qf1, s1, 0, 0, 0);
    s0 = __builtin_amdgcn_mfma_f32_32x32x16_bf16(kf[0][2], qf2, s0, 0, 0, 0);
    s1 = __builtin_amdgcn_mfma_f32_32x32x16_bf16(kf[1][2], qf2, s1, 0, 0, 0);
    s0 = __builtin_amdgcn_mfma_f32_32x32x16_bf16(kf[0][3], qf3, s0, 0, 0, 0);
    s1 = __builtin_amdgcn_mfma_f32_32x32x16_bf16(kf[1][3], qf3, s1, 0, 0, 0);

    // prefetch next K tile under the softmax
    if (jt + 1 < hiB) {
#pragma unroll
      for (int ss = 0; ss < 2; ++ss)
#pragma unroll
        for (int c = 0; c < 4; ++c)
          kf[ss][c] = *(const bf16x8*)(Kbase + (size_t)((jt + 1) * 64 + ss * 32) * 64 + c * 16);
    }

    // causal mask (only the diagonal tile)
    if (jt == jtmax) {
      const int qrel = l31 + (qb - jtmax * 64);  // 0..31 (qt even) or 32..63 (qt odd)
      const int h4 = hi * 4;
#pragma unroll
      for (int r = 0; r < 16; ++r) {
        const int kp = (r & 3) + ((r >> 2) << 3) + h4;
        s0[r] = (kp <= qrel) ? s0[r] : -1e30f;
        s1[r] = (kp + 32 <= qrel) ? s1[r] : -1e30f;
      }
    }

    // ---- in-register online softmax (per lane = one q-row's 32 kpos) ----
    float t8[8];
#pragma unroll
    for (int r = 0; r < 8; ++r)
      t8[r] = fmaxf(fmaxf(s0[r], s0[r + 8]), fmaxf(s1[r], s1[r + 8]));
    float tm = fmaxf(fmaxf(fmaxf(t8[0], t8[1]), fmaxf(t8[2], t8[3])),
                     fmaxf(fmaxf(t8[4], t8[5]), fmaxf(t8[6], t8[7])));
    tm = fmaxf(tm, __shfl_xor(tm, 32));
    if (!__all(tm <= mrun)) {
      const float mnew = fmaxf(mrun, tm);
      const float al = fast_exp2((mrun - mnew) * SC);
      mrun = mnew;
      lrun *= al;
#pragma unroll
      for (int r = 0; r < 16; ++r) { o0[r] *= al; o1[r] *= al; }
    }
    const float nb = -mrun * SC;
#pragma unroll
    for (int r = 0; r < 16; ++r) {
      s0[r] = fast_exp2(fmaf(s0[r], SC, nb));
      s1[r] = fast_exp2(fmaf(s1[r], SC, nb));
    }
    float u8[8];
#pragma unroll
    for (int r = 0; r < 8; ++r)
      u8[r] = (s0[r] + s0[r + 8]) + (s1[r] + s1[r + 8]);
    lrun += ((u8[0] + u8[1]) + (u8[2] + u8[3])) + ((u8[4] + u8[5]) + (u8[6] + u8[7]));

    // ---- pack P to bf16 B-fragments (cvt_pk + permlane32_swap, T12) ----
    bf16x8 pb0, pb1, pb2, pb3;
#define PACK_CHUNK(sv, bb, dst)                                   \
    {                                                             \
      u32 a0 = cvtpk(sv[bb + 0], sv[bb + 1]);                     \
      u32 a1 = cvtpk(sv[bb + 2], sv[bb + 3]);                     \
      u32 a2 = cvtpk(sv[bb + 4], sv[bb + 5]);                     \
      u32 a3 = cvtpk(sv[bb + 6], sv[bb + 7]);                     \
      plswap(a0, a2);                                             \
      plswap(a1, a3);                                             \
      u32x4 fv = {a0, a1, a2, a3};                                \
      dst = __builtin_bit_cast(bf16x8, fv);                       \
    }
    PACK_CHUNK(s0, 0, pb0)
    PACK_CHUNK(s0, 8, pb1)
    PACK_CHUNK(s1, 0, pb2)
    PACK_CHUNK(s1, 8, pb3)
#undef PACK_CHUNK

    // ---- O^T[d][q] += V^T . P^T ----
    o0 = __builtin_amdgcn_mfma_f32_32x32x16_bf16(vf[0][0], pb0, o0, 0, 0, 0);
    o1 = __builtin_amdgcn_mfma_f32_32x32x16_bf16(vf[1][0], pb0, o1, 0, 0, 0);
    o0 = __builtin_amdgcn_mfma_f32_32x32x16_bf16(vf[0][1], pb1, o0, 0, 0, 0);
    o1 = __builtin_amdgcn_mfma_f32_32x32x16_bf16(vf[1][1], pb1, o1, 0, 0, 0);
    o0 = __builtin_amdgcn_mfma_f32_32x32x16_bf16(vf[0][2], pb2, o0, 0, 0, 0);
    o1 = __builtin_amdgcn_mfma_f32_32x32x16_bf16(vf[1][2], pb2, o1, 0, 0, 0);
    o0 = __builtin_amdgcn_mfma_f32_32x32x16_bf16(vf[0][3], pb3, o0, 0, 0, 0);
    o1 = __builtin_amdgcn_mfma_f32_32x32x16_bf16(vf[1][3], pb3, o1, 0, 0, 0);
  }

  // ---- cross-wave flash combine (one LDS round) ----
  if (s) {
#pragma unroll
    for (int r = 0; r < 16; ++r) {
      Osl[ti][r][lane]      = o0[r];
      Osl[ti][16 + r][lane] = o1[r];
    }
    Msl[ti][lane] = mrun;
    Lsl[ti][lane] = lrun;
  }
  __syncthreads();
  if (s) return;

  {
    const float mB = Msl[ti][lane];
    const float lB = Lsl[ti][lane];
    const float m  = fmaxf(mrun, mB);
    const float al = fast_exp2((mrun - m) * SC);
    const float bt = fast_exp2((mB - m) * SC);
    lrun = lrun * al + lB * bt;
#pragma unroll
    for (int r = 0; r < 16; ++r) {
      o0[r] = o0[r] * al + Osl[ti][r][lane] * bt;
      o1[r] = o1[r] * al + Osl[ti][16 + r][lane] * bt;
    }
  }

  // ---- epilogue: combine partner row-sums, normalize, store bf16 ----
  const float lt = lrun + __shfl_xor(lrun, 32);
  const float inv = 1.0f / lt;
  u16* aorow = AO + (size_t)(b * 2048 + qb + l31) * 1024 + h * 64 + hi * 4;
#pragma unroll
  for (int g = 0; g < 4; ++g) {
    u32 w0 = cvtpk(o0[4 * g + 0] * inv, o0[4 * g + 1] * inv);
    u32 w1 = cvtpk(o0[4 * g + 2] * inv, o0[4 * g + 3] * inv);
    u32x2 ww = {w0, w1};
    *(u32x2*)(aorow + g * 8) = ww;
  }
#pragma unroll
  for (int g = 0; g < 4; ++g) {
    u32 w0 = cvtpk(o1[4 * g + 0] * inv, o1[4 * g + 1] * inv);
    u32 w1 = cvtpk(o1[4 * g + 2] * inv, o1[4 * g + 3] * inv);
    u32x2 ww = {w0, w1};
    *(u32x2*)(aorow + 32 + g * 8) = ww;
  }
}

extern "C" void kernel_launch(void* const* d_in, const int* in_sizes, int n_in,
                              void* d_out, int out_size, void* d_ws, size_t ws_size,
                              hipStream_t stream) {
  const float* x      = (const float*)d_in[0];
  const float* w_attn = (const float*)d_in[1];
  const float* b_attn = (const float*)d_in[2];
  const float* w_proj = (const float*)d_in[3];
  const float* b_proj = (const float*)d_in[4];
  float* out = (float*)d_out;

  char* ws = (char*)d_ws;
  u16* x_bf  = (u16*)(ws);                    // [4096][1024] bf16   (8 MB)
  u16* wat_t = (u16*)(ws + 8388608);          // [3072][1024] bf16   (6 MB)
  u16* wpj_t = (u16*)(ws + 14680064);         // [1024][1024] bf16   (2 MB)
  u16* q_ws  = (u16*)(ws + 16777216);         // [B,H,S,d] bf16      (8 MB)
  u16* k_ws  = (u16*)(ws + 25165824);         // [B,H,S,d] bf16      (8 MB)
  u16* vT_ws = (u16*)(ws + 33554432);         // [B,H,d,S] bf16      (8 MB)
  u16* a_ws  = (u16*)(ws + 41943040);         // [B,S,nx]  bf16      (8 MB)

  k_cvt<<<4096, 256, 0, stream>>>(x, x_bf, 4194304);
  k_tcvt<<<dim3(96, 32), dim3(32, 8), 0, stream>>>(w_attn, wat_t, 1024, 3072);
  k_tcvt<<<dim3(32, 32), dim3(32, 8), 0, stream>>>(w_proj, wpj_t, 1024, 1024);

  k_gemm<0><<<dim3(24, 32), 256, 0, stream>>>(x_bf, wat_t, b_attn,
                                              q_ws, k_ws, vT_ws,
                                              out + 4194304, out + 8388608, nullptr);

  k_attn<<<dim3(1024), 256, 0, stream>>>(q_ws, k_ws, vT_ws, a_ws);

  k_gemm<1><<<dim3(8, 32), 256, 0, stream>>>(a_ws, wpj_t, b_proj,
                                             nullptr, nullptr, nullptr,
                                             nullptr, nullptr, out);
}

// Round 4
// 165.154 us; speedup vs baseline: 1.4068x; 1.4068x over previous
//
#include <hip/hip_runtime.h>
#include <stdint.h>
#include <stddef.h>

#define DEVI __device__ __forceinline__

typedef __bf16 bf16x8 __attribute__((ext_vector_type(8)));
typedef float  f32x4  __attribute__((ext_vector_type(4)));
typedef float  f32x16 __attribute__((ext_vector_type(16)));
typedef unsigned short u16;
typedef uint32_t u32;
typedef u16 u16x8 __attribute__((ext_vector_type(8)));
typedef u16 u16x4 __attribute__((ext_vector_type(4)));
typedef u32 u32x2 __attribute__((ext_vector_type(2)));
typedef u32 u32x4 __attribute__((ext_vector_type(4)));

typedef __attribute__((address_space(1))) void as1_void;
typedef __attribute__((address_space(3))) void as3_void;

static constexpr float SC = 0.18033688011112042f;  // (1/8) * log2(e)

DEVI u16 f2bf(float f) {
  uint32_t u = __builtin_bit_cast(uint32_t, f);
  u += 0x7fffu + ((u >> 16) & 1u);
  return (u16)(u >> 16);
}

DEVI void gload_lds16(const void* g, void* l) {
  __builtin_amdgcn_global_load_lds((as1_void*)(void*)g, (as3_void*)l, 16, 0, 0);
}

#if __has_builtin(__builtin_amdgcn_exp2f)
DEVI float fast_exp2(float x) { return __builtin_amdgcn_exp2f(x); }
#else
DEVI float fast_exp2(float x) { return exp2f(x); }
#endif

DEVI u32 cvtpk(float lo, float hi) {
  u32 r;
  asm("v_cvt_pk_bf16_f32 %0, %1, %2" : "=v"(r) : "v"(lo), "v"(hi));
  return r;
}
DEVI void plswap(u32& a, u32& b) {
  asm("v_permlane32_swap_b32 %0, %1" : "+v"(a), "+v"(b));
}

// ---------------- elementwise fp32 -> bf16 ----------------
__global__ __launch_bounds__(256) void k_cvt(const float* __restrict__ in,
                                             u16* __restrict__ out, int n) {
  int i = (blockIdx.x * 256 + threadIdx.x) * 4;
  if (i >= n) return;
  const float4 v = *(const float4*)(in + i);
  u16x4 o = { f2bf(v.x), f2bf(v.y), f2bf(v.z), f2bf(v.w) };
  *(u16x4*)(out + i) = o;
}

// ------------- transpose + convert: in fp32 [R][C] -> out bf16 [C][R] -------------
__global__ __launch_bounds__(256) void k_tcvt(const float* __restrict__ in,
                                              u16* __restrict__ out, int R, int C) {
  __shared__ float tile[32][33];
  const int c0 = blockIdx.x * 32, r0 = blockIdx.y * 32;
  const int tx = threadIdx.x, ty = threadIdx.y;
#pragma unroll
  for (int i = ty; i < 32; i += 8)
    tile[i][tx] = in[(size_t)(r0 + i) * C + (c0 + tx)];
  __syncthreads();
#pragma unroll
  for (int i = ty; i < 32; i += 8)
    out[(size_t)(c0 + i) * R + (r0 + tx)] = f2bf(tile[tx][i]);
}

// ---------------- GEMM: C[M][N] = A[M][K] * Bt[N][K]^T  (bf16 in, fp32 acc) ----------------
// EPI 0: qkv epilogue (q,k bf16 [B,H,S,d]; v -> vT bf16 [B,H,d,S]; present fp32)
// EPI 1: proj epilogue (fp32 out + bias)
template <int EPI>
__global__ __launch_bounds__(256) void k_gemm(
    const u16* __restrict__ A, const u16* __restrict__ Bt,
    const float* __restrict__ bias,
    u16* __restrict__ wq, u16* __restrict__ wk, u16* __restrict__ vt,
    float* __restrict__ pk, float* __restrict__ pv, float* __restrict__ of) {
  constexpr int K = 1024;
  __shared__ __align__(16) u16 Ash[128 * 32];
  __shared__ __align__(16) u16 Bsh[128 * 32];
  const int tid = threadIdx.x;
  const int lane = tid & 63, wid = tid >> 6;
  const int wm = wid >> 1, wn = wid & 1;
  const int lr = lane & 15, lg = lane >> 4;
  const int m0 = blockIdx.y * 128, n0 = blockIdx.x * 128;

  const int c = wid * 64 + lane;  // 16B chunk id, 0..255
  const u16* Ag1 = A + (size_t)(m0 + (c >> 2)) * K + (c & 3) * 8;
  const u16* Ag2 = A + (size_t)(m0 + 64 + (c >> 2)) * K + (c & 3) * 8;
  const u16* Bg1 = Bt + (size_t)(n0 + (c >> 2)) * K + (c & 3) * 8;
  const u16* Bg2 = Bt + (size_t)(n0 + 64 + (c >> 2)) * K + (c & 3) * 8;
  u16* Ad1 = Ash + wid * 512;
  u16* Ad2 = Ash + 2048 + wid * 512;
  u16* Bd1 = Bsh + wid * 512;
  u16* Bd2 = Bsh + 2048 + wid * 512;

  f32x4 acc[4][4];
#pragma unroll
  for (int i = 0; i < 4; ++i)
#pragma unroll
    for (int j = 0; j < 4; ++j) acc[i][j] = (f32x4)0.0f;

  for (int k0 = 0; k0 < K; k0 += 32) {
    gload_lds16(Ag1 + k0, Ad1);
    gload_lds16(Ag2 + k0, Ad2);
    gload_lds16(Bg1 + k0, Bd1);
    gload_lds16(Bg2 + k0, Bd2);
    __syncthreads();
    bf16x8 af[4], bfr[4];
#pragma unroll
    for (int f = 0; f < 4; ++f) {
      af[f]  = *(const bf16x8*)&Ash[(wm * 64 + f * 16 + lr) * 32 + lg * 8];
      bfr[f] = *(const bf16x8*)&Bsh[(wn * 64 + f * 16 + lr) * 32 + lg * 8];
    }
#pragma unroll
    for (int i = 0; i < 4; ++i)
#pragma unroll
      for (int j = 0; j < 4; ++j)
        acc[i][j] = __builtin_amdgcn_mfma_f32_16x16x32_bf16(af[i], bfr[j], acc[i][j], 0, 0, 0);
    __syncthreads();
  }

  if constexpr (EPI == 0) {
#pragma unroll
    for (int j = 0; j < 4; ++j) {
      const int n = n0 + wn * 64 + j * 16 + lr;
      const float bv = bias[n];
      const int sec = n >> 10;
      const int nn = n & 1023;
      const int h = nn >> 6, dd = nn & 63;
#pragma unroll
      for (int i = 0; i < 4; ++i) {
        const int mb = m0 + wm * 64 + i * 16 + lg * 4;
        const int bb = mb >> 11, ss = mb & 2047;
        const size_t ib = (size_t)(bb * 16 + h) * 131072 + (size_t)ss * 64 + dd;
        if (sec == 0) {
#pragma unroll
          for (int r = 0; r < 4; ++r)
            wq[ib + (size_t)r * 64] = f2bf(acc[i][j][r] + bv);
        } else if (sec == 1) {
#pragma unroll
          for (int r = 0; r < 4; ++r) {
            const float v = acc[i][j][r] + bv;
            wk[ib + (size_t)r * 64] = f2bf(v);
            pk[ib + (size_t)r * 64] = v;
          }
        } else {
          u16x4 vv;
#pragma unroll
          for (int r = 0; r < 4; ++r) {
            const float v = acc[i][j][r] + bv;
            pv[ib + (size_t)r * 64] = v;
            vv[r] = f2bf(v);
          }
          *(u16x4*)(vt + ((size_t)(bb * 16 + h) * 64 + dd) * 2048 + ss) = vv;
        }
      }
    }
  } else {
#pragma unroll
    for (int j = 0; j < 4; ++j) {
      const int n = n0 + wn * 64 + j * 16 + lr;
      const float bv = bias[n];
#pragma unroll
      for (int i = 0; i < 4; ++i) {
        const int mb = m0 + wm * 64 + i * 16 + lg * 4;
#pragma unroll
        for (int r = 0; r < 4; ++r)
          of[(size_t)(mb + r) * 1024 + n] = acc[i][j][r] + bv;
      }
    }
  }
}

// ---------------- causal flash attention, swapped-QK^T, KV-split ----------------
// 1024 blocks x 256 thr. Block = (bh = bid&31, pair = bid>>5).
// Waves 0,1 -> q-tile `pair` (32 rows); waves 2,3 -> q-tile `63-pair`.
// Each wave does half the tile's KV range with its own online-softmax partial;
// partials merge once via LDS (flash combine). 4096 waves; launch_bounds(256,2)
// -> VGPR cap 256 (kernel needs ~190: NO spill; round-3's (256,4) spilled).
__global__ __launch_bounds__(256, 2) void k_attn(const u16* __restrict__ Q,
                                                 const u16* __restrict__ Kp,
                                                 const u16* __restrict__ VT,
                                                 u16* __restrict__ AO) {
  __shared__ float Osl[2][32][64];
  __shared__ float Msl[2][64];
  __shared__ float Lsl[2][64];

  const int tid = threadIdx.x;
  const int lane = tid & 63, w = tid >> 6;
  const int l31 = lane & 31, hi = lane >> 5;
  const int s = w & 1, ti = w >> 1;
  const int bh = blockIdx.x & 31;          // bh%8 == bid%8 -> bh pinned per-XCD
  const int pair = blockIdx.x >> 5;        // 0..31
  const int b = bh >> 4, h = bh & 15;
  const size_t hb = (size_t)bh * (2048 * 64);

  const int qt = ti ? (63 - pair) : pair;
  const int qb = qt * 32;
  const int T = (qt >> 1) + 1;             // # of 64-wide KV tiles
  const int mid = (T + 1) >> 1;
  const int lo = s ? mid : 0;
  const int hiB = s ? T : mid;
  const int jtmax = T - 1;                 // diagonal tile index

  const u16* Kbase = Kp + hb + (size_t)l31 * 64 + hi * 8;
  const u16* Vbase = VT + hb + (size_t)l31 * 2048 + hi * 8;
  const u16* Qbase = Q  + hb + (size_t)l31 * 64 + hi * 8;

  const bf16x8 qf0 = *(const bf16x8*)(Qbase + (size_t)qb * 64);
  const bf16x8 qf1 = *(const bf16x8*)(Qbase + (size_t)qb * 64 + 16);
  const bf16x8 qf2 = *(const bf16x8*)(Qbase + (size_t)qb * 64 + 32);
  const bf16x8 qf3 = *(const bf16x8*)(Qbase + (size_t)qb * 64 + 48);

  f32x16 o0 = (f32x16)0.0f, o1 = (f32x16)0.0f;
  float mrun = -1e30f, lrun = 0.0f;

  bf16x8 kf[2][4];
#pragma unroll
  for (int ss = 0; ss < 2; ++ss)
#pragma unroll
    for (int c = 0; c < 4; ++c)
      kf[ss][c] = *(const bf16x8*)(Kbase + (size_t)(lo * 64 + ss * 32) * 64 + c * 16);

  for (int jt = lo; jt < hiB; ++jt) {
    // V^T fragments for this KV tile (used at the end -> latency hidden)
    bf16x8 vf[2][4];
#pragma unroll
    for (int mt = 0; mt < 2; ++mt)
#pragma unroll
      for (int c = 0; c < 4; ++c)
        vf[mt][c] = *(const bf16x8*)(Vbase + (size_t)(mt * 32) * 2048 + jt * 64 + c * 16);

    // S^T[kpos][q] = K . Q^T
    f32x16 s0 = (f32x16)0.0f, s1 = (f32x16)0.0f;
    s0 = __builtin_amdgcn_mfma_f32_32x32x16_bf16(kf[0][0], qf0, s0, 0, 0, 0);
    s1 = __builtin_amdgcn_mfma_f32_32x32x16_bf16(kf[1][0], qf0, s1, 0, 0, 0);
    s0 = __builtin_amdgcn_mfma_f32_32x32x16_bf16(kf[0][1], qf1, s0, 0, 0, 0);
    s1 = __builtin_amdgcn_mfma_f32_32x32x16_bf16(kf[1][1], qf1, s1, 0, 0, 0);
    s0 = __builtin_amdgcn_mfma_f32_32x32x16_bf16(kf[0][2], qf2, s0, 0, 0, 0);
    s1 = __builtin_amdgcn_mfma_f32_32x32x16_bf16(kf[1][2], qf2, s1, 0, 0, 0);
    s0 = __builtin_amdgcn_mfma_f32_32x32x16_bf16(kf[0][3], qf3, s0, 0, 0, 0);
    s1 = __builtin_amdgcn_mfma_f32_32x32x16_bf16(kf[1][3], qf3, s1, 0, 0, 0);

    // prefetch next K tile under the softmax
    if (jt + 1 < hiB) {
#pragma unroll
      for (int ss = 0; ss < 2; ++ss)
#pragma unroll
        for (int c = 0; c < 4; ++c)
          kf[ss][c] = *(const bf16x8*)(Kbase + (size_t)((jt + 1) * 64 + ss * 32) * 64 + c * 16);
    }

    // causal mask (only the diagonal tile)
    if (jt == jtmax) {
      const int qrel = l31 + (qb - jtmax * 64);  // 0..31 (qt even) or 32..63 (qt odd)
      const int h4 = hi * 4;
#pragma unroll
      for (int r = 0; r < 16; ++r) {
        const int kp = (r & 3) + ((r >> 2) << 3) + h4;
        s0[r] = (kp <= qrel) ? s0[r] : -1e30f;
        s1[r] = (kp + 32 <= qrel) ? s1[r] : -1e30f;
      }
    }

    // ---- in-register online softmax (per lane = one q-row's 32 kpos) ----
    float t8[8];
#pragma unroll
    for (int r = 0; r < 8; ++r)
      t8[r] = fmaxf(fmaxf(s0[r], s0[r + 8]), fmaxf(s1[r], s1[r + 8]));
    float tm = fmaxf(fmaxf(fmaxf(t8[0], t8[1]), fmaxf(t8[2], t8[3])),
                     fmaxf(fmaxf(t8[4], t8[5]), fmaxf(t8[6], t8[7])));
    tm = fmaxf(tm, __shfl_xor(tm, 32));
    if (!__all(tm <= mrun)) {
      const float mnew = fmaxf(mrun, tm);
      const float al = fast_exp2((mrun - mnew) * SC);
      mrun = mnew;
      lrun *= al;
#pragma unroll
      for (int r = 0; r < 16; ++r) { o0[r] *= al; o1[r] *= al; }
    }
    const float nb = -mrun * SC;
#pragma unroll
    for (int r = 0; r < 16; ++r) {
      s0[r] = fast_exp2(fmaf(s0[r], SC, nb));
      s1[r] = fast_exp2(fmaf(s1[r], SC, nb));
    }
    float u8[8];
#pragma unroll
    for (int r = 0; r < 8; ++r)
      u8[r] = (s0[r] + s0[r + 8]) + (s1[r] + s1[r + 8]);
    lrun += ((u8[0] + u8[1]) + (u8[2] + u8[3])) + ((u8[4] + u8[5]) + (u8[6] + u8[7]));

    // ---- pack P to bf16 B-fragments (cvt_pk + permlane32_swap, T12) ----
    bf16x8 pb0, pb1, pb2, pb3;
#define PACK_CHUNK(sv, bb, dst)                                   \
    {                                                             \
      u32 a0 = cvtpk(sv[bb + 0], sv[bb + 1]);                     \
      u32 a1 = cvtpk(sv[bb + 2], sv[bb + 3]);                     \
      u32 a2 = cvtpk(sv[bb + 4], sv[bb + 5]);                     \
      u32 a3 = cvtpk(sv[bb + 6], sv[bb + 7]);                     \
      plswap(a0, a2);                                             \
      plswap(a1, a3);                                             \
      u32x4 fv = {a0, a1, a2, a3};                                \
      dst = __builtin_bit_cast(bf16x8, fv);                       \
    }
    PACK_CHUNK(s0, 0, pb0)
    PACK_CHUNK(s0, 8, pb1)
    PACK_CHUNK(s1, 0, pb2)
    PACK_CHUNK(s1, 8, pb3)
#undef PACK_CHUNK

    // ---- O^T[d][q] += V^T . P^T ----
    o0 = __builtin_amdgcn_mfma_f32_32x32x16_bf16(vf[0][0], pb0, o0, 0, 0, 0);
    o1 = __builtin_amdgcn_mfma_f32_32x32x16_bf16(vf[1][0], pb0, o1, 0, 0, 0);
    o0 = __builtin_amdgcn_mfma_f32_32x32x16_bf16(vf[0][1], pb1, o0, 0, 0, 0);
    o1 = __builtin_amdgcn_mfma_f32_32x32x16_bf16(vf[1][1], pb1, o1, 0, 0, 0);
    o0 = __builtin_amdgcn_mfma_f32_32x32x16_bf16(vf[0][2], pb2, o0, 0, 0, 0);
    o1 = __builtin_amdgcn_mfma_f32_32x32x16_bf16(vf[1][2], pb2, o1, 0, 0, 0);
    o0 = __builtin_amdgcn_mfma_f32_32x32x16_bf16(vf[0][3], pb3, o0, 0, 0, 0);
    o1 = __builtin_amdgcn_mfma_f32_32x32x16_bf16(vf[1][3], pb3, o1, 0, 0, 0);
  }

  // ---- cross-wave flash combine (one LDS round) ----
  if (s) {
#pragma unroll
    for (int r = 0; r < 16; ++r) {
      Osl[ti][r][lane]      = o0[r];
      Osl[ti][16 + r][lane] = o1[r];
    }
    Msl[ti][lane] = mrun;
    Lsl[ti][lane] = lrun;
  }
  __syncthreads();
  if (s) return;

  {
    const float mB = Msl[ti][lane];
    const float lB = Lsl[ti][lane];
    const float m  = fmaxf(mrun, mB);
    const float al = fast_exp2((mrun - m) * SC);
    const float bt = fast_exp2((mB - m) * SC);
    lrun = lrun * al + lB * bt;
#pragma unroll
    for (int r = 0; r < 16; ++r) {
      o0[r] = o0[r] * al + Osl[ti][r][lane] * bt;
      o1[r] = o1[r] * al + Osl[ti][16 + r][lane] * bt;
    }
  }

  // ---- epilogue: combine partner row-sums, normalize, store bf16 ----
  const float lt = lrun + __shfl_xor(lrun, 32);
  const float inv = 1.0f / lt;
  u16* aorow = AO + (size_t)(b * 2048 + qb + l31) * 1024 + h * 64 + hi * 4;
#pragma unroll
  for (int g = 0; g < 4; ++g) {
    u32 w0 = cvtpk(o0[4 * g + 0] * inv, o0[4 * g + 1] * inv);
    u32 w1 = cvtpk(o0[4 * g + 2] * inv, o0[4 * g + 3] * inv);
    u32x2 ww = {w0, w1};
    *(u32x2*)(aorow + g * 8) = ww;
  }
#pragma unroll
  for (int g = 0; g < 4; ++g) {
    u32 w0 = cvtpk(o1[4 * g + 0] * inv, o1[4 * g + 1] * inv);
    u32 w1 = cvtpk(o1[4 * g + 2] * inv, o1[4 * g + 3] * inv);
    u32x2 ww = {w0, w1};
    *(u32x2*)(aorow + 32 + g * 8) = ww;
  }
}

extern "C" void kernel_launch(void* const* d_in, const int* in_sizes, int n_in,
                              void* d_out, int out_size, void* d_ws, size_t ws_size,
                              hipStream_t stream) {
  const float* x      = (const float*)d_in[0];
  const float* w_attn = (const float*)d_in[1];
  const float* b_attn = (const float*)d_in[2];
  const float* w_proj = (const float*)d_in[3];
  const float* b_proj = (const float*)d_in[4];
  float* out = (float*)d_out;

  char* ws = (char*)d_ws;
  u16* x_bf  = (u16*)(ws);                    // [4096][1024] bf16   (8 MB)
  u16* wat_t = (u16*)(ws + 8388608);          // [3072][1024] bf16   (6 MB)
  u16* wpj_t = (u16*)(ws + 14680064);         // [1024][1024] bf16   (2 MB)
  u16* q_ws  = (u16*)(ws + 16777216);         // [B,H,S,d] bf16      (8 MB)
  u16* k_ws  = (u16*)(ws + 25165824);         // [B,H,S,d] bf16      (8 MB)
  u16* vT_ws = (u16*)(ws + 33554432);         // [B,H,d,S] bf16      (8 MB)
  u16* a_ws  = (u16*)(ws + 41943040);         // [B,S,nx]  bf16      (8 MB)

  k_cvt<<<4096, 256, 0, stream>>>(x, x_bf, 4194304);
  k_tcvt<<<dim3(96, 32), dim3(32, 8), 0, stream>>>(w_attn, wat_t, 1024, 3072);
  k_tcvt<<<dim3(32, 32), dim3(32, 8), 0, stream>>>(w_proj, wpj_t, 1024, 1024);

  k_gemm<0><<<dim3(24, 32), 256, 0, stream>>>(x_bf, wat_t, b_attn,
                                              q_ws, k_ws, vT_ws,
                                              out + 4194304, out + 8388608, nullptr);

  k_attn<<<dim3(1024), 256, 0, stream>>>(q_ws, k_ws, vT_ws, a_ws);

  k_gemm<1><<<dim3(8, 32), 256, 0, stream>>>(a_ws, wpj_t, b_proj,
                                             nullptr, nullptr, nullptr,
                                             nullptr, nullptr, out);
}

// Round 5
// 154.026 us; speedup vs baseline: 1.5085x; 1.0722x over previous
//
#include <hip/hip_runtime.h>
#include <stdint.h>
#include <stddef.h>

#define DEVI __device__ __forceinline__

typedef __bf16 bf16x8 __attribute__((ext_vector_type(8)));
typedef float  f32x4  __attribute__((ext_vector_type(4)));
typedef float  f32x16 __attribute__((ext_vector_type(16)));
typedef unsigned short u16;
typedef uint32_t u32;
typedef u16 u16x8 __attribute__((ext_vector_type(8)));
typedef u16 u16x4 __attribute__((ext_vector_type(4)));
typedef u32 u32x2 __attribute__((ext_vector_type(2)));
typedef u32 u32x4 __attribute__((ext_vector_type(4)));

typedef __attribute__((address_space(1))) void as1_void;
typedef __attribute__((address_space(3))) void as3_void;

static constexpr float SC = 0.18033688011112042f;  // (1/8) * log2(e)

DEVI u16 f2bf(float f) {
  uint32_t u = __builtin_bit_cast(uint32_t, f);
  u += 0x7fffu + ((u >> 16) & 1u);
  return (u16)(u >> 16);
}

DEVI void gload_lds16(const void* g, void* l) {
  __builtin_amdgcn_global_load_lds((as1_void*)(void*)g, (as3_void*)l, 16, 0, 0);
}

#if __has_builtin(__builtin_amdgcn_exp2f)
DEVI float fast_exp2(float x) { return __builtin_amdgcn_exp2f(x); }
#else
DEVI float fast_exp2(float x) { return exp2f(x); }
#endif

DEVI u32 cvtpk(float lo, float hi) {
  u32 r;
  asm("v_cvt_pk_bf16_f32 %0, %1, %2" : "=v"(r) : "v"(lo), "v"(hi));
  return r;
}
DEVI void plswap(u32& a, u32& b) {
  asm("v_permlane32_swap_b32 %0, %1" : "+v"(a), "+v"(b));
}

// ---------------- elementwise fp32 -> bf16 ----------------
__global__ __launch_bounds__(256) void k_cvt(const float* __restrict__ in,
                                             u16* __restrict__ out, int n) {
  int i = (blockIdx.x * 256 + threadIdx.x) * 4;
  if (i >= n) return;
  const float4 v = *(const float4*)(in + i);
  u16x4 o = { f2bf(v.x), f2bf(v.y), f2bf(v.z), f2bf(v.w) };
  *(u16x4*)(out + i) = o;
}

// ------------- transpose + convert: in fp32 [R][C] -> out bf16 [C][R] -------------
__global__ __launch_bounds__(256) void k_tcvt(const float* __restrict__ in,
                                              u16* __restrict__ out, int R, int C) {
  __shared__ float tile[32][33];
  const int c0 = blockIdx.x * 32, r0 = blockIdx.y * 32;
  const int tx = threadIdx.x, ty = threadIdx.y;
#pragma unroll
  for (int i = ty; i < 32; i += 8)
    tile[i][tx] = in[(size_t)(r0 + i) * C + (c0 + tx)];
  __syncthreads();
#pragma unroll
  for (int i = ty; i < 32; i += 8)
    out[(size_t)(c0 + i) * R + (r0 + tx)] = f2bf(tile[tx][i]);
}

// ---------------- GEMM: C[M][N] = A[M][K] * Bt[N][K]^T  (bf16 in, fp32 acc) ----------------
// 2-phase double-buffered staging: issue global_load_lds for tile t+1 BEFORE
// computing tile t; the single __syncthreads per K-step (vmcnt(0) drain) lands
// after the full MFMA phase instead of immediately after load-issue.
// EPI 0: qkv epilogue (q,k bf16 [B,H,S,d]; v -> vT bf16 [B,H,d,S]; present fp32)
// EPI 1: proj epilogue (fp32 out + bias)
template <int EPI>
__global__ __launch_bounds__(256) void k_gemm(
    const u16* __restrict__ A, const u16* __restrict__ Bt,
    const float* __restrict__ bias,
    u16* __restrict__ wq, u16* __restrict__ wk, u16* __restrict__ vt,
    float* __restrict__ pk, float* __restrict__ pv, float* __restrict__ of) {
  constexpr int K = 1024;
  __shared__ __align__(16) u16 Ash[2][128 * 32];
  __shared__ __align__(16) u16 Bsh[2][128 * 32];
  const int tid = threadIdx.x;
  const int lane = tid & 63, wid = tid >> 6;
  const int wm = wid >> 1, wn = wid & 1;
  const int lr = lane & 15, lg = lane >> 4;
  const int m0 = blockIdx.y * 128, n0 = blockIdx.x * 128;

  const int c = wid * 64 + lane;  // 16B chunk id, 0..255
  const u16* Ag1 = A + (size_t)(m0 + (c >> 2)) * K + (c & 3) * 8;
  const u16* Ag2 = A + (size_t)(m0 + 64 + (c >> 2)) * K + (c & 3) * 8;
  const u16* Bg1 = Bt + (size_t)(n0 + (c >> 2)) * K + (c & 3) * 8;
  const u16* Bg2 = Bt + (size_t)(n0 + 64 + (c >> 2)) * K + (c & 3) * 8;

  f32x4 acc[4][4];
#pragma unroll
  for (int i = 0; i < 4; ++i)
#pragma unroll
    for (int j = 0; j < 4; ++j) acc[i][j] = (f32x4)0.0f;

#define STAGE(sel, kk)                                        \
  {                                                           \
    gload_lds16(Ag1 + (kk), &Ash[sel][wid * 512]);            \
    gload_lds16(Ag2 + (kk), &Ash[sel][2048 + wid * 512]);     \
    gload_lds16(Bg1 + (kk), &Bsh[sel][wid * 512]);            \
    gload_lds16(Bg2 + (kk), &Bsh[sel][2048 + wid * 512]);     \
  }

  STAGE(0, 0)
  __syncthreads();
  int cur = 0;
  for (int k0 = 0; k0 < K; k0 += 32) {
    if (k0 + 32 < K) STAGE(cur ^ 1, k0 + 32)
    bf16x8 af[4], bfr[4];
#pragma unroll
    for (int f = 0; f < 4; ++f) {
      af[f]  = *(const bf16x8*)&Ash[cur][(wm * 64 + f * 16 + lr) * 32 + lg * 8];
      bfr[f] = *(const bf16x8*)&Bsh[cur][(wn * 64 + f * 16 + lr) * 32 + lg * 8];
    }
#pragma unroll
    for (int i = 0; i < 4; ++i)
#pragma unroll
      for (int j = 0; j < 4; ++j)
        acc[i][j] = __builtin_amdgcn_mfma_f32_16x16x32_bf16(af[i], bfr[j], acc[i][j], 0, 0, 0);
    __syncthreads();  // drains next-tile loads (vmcnt0) + protects buffer reuse
    cur ^= 1;
  }
#undef STAGE

  if constexpr (EPI == 0) {
#pragma unroll
    for (int j = 0; j < 4; ++j) {
      const int n = n0 + wn * 64 + j * 16 + lr;
      const float bv = bias[n];
      const int sec = n >> 10;
      const int nn = n & 1023;
      const int h = nn >> 6, dd = nn & 63;
#pragma unroll
      for (int i = 0; i < 4; ++i) {
        const int mb = m0 + wm * 64 + i * 16 + lg * 4;
        const int bb = mb >> 11, ss = mb & 2047;
        const size_t ib = (size_t)(bb * 16 + h) * 131072 + (size_t)ss * 64 + dd;
        if (sec == 0) {
#pragma unroll
          for (int r = 0; r < 4; ++r)
            wq[ib + (size_t)r * 64] = f2bf(acc[i][j][r] + bv);
        } else if (sec == 1) {
#pragma unroll
          for (int r = 0; r < 4; ++r) {
            const float v = acc[i][j][r] + bv;
            wk[ib + (size_t)r * 64] = f2bf(v);
            pk[ib + (size_t)r * 64] = v;
          }
        } else {
          u16x4 vv;
#pragma unroll
          for (int r = 0; r < 4; ++r) {
            const float v = acc[i][j][r] + bv;
            pv[ib + (size_t)r * 64] = v;
            vv[r] = f2bf(v);
          }
          *(u16x4*)(vt + ((size_t)(bb * 16 + h) * 64 + dd) * 2048 + ss) = vv;
        }
      }
    }
  } else {
#pragma unroll
    for (int j = 0; j < 4; ++j) {
      const int n = n0 + wn * 64 + j * 16 + lr;
      const float bv = bias[n];
#pragma unroll
      for (int i = 0; i < 4; ++i) {
        const int mb = m0 + wm * 64 + i * 16 + lg * 4;
#pragma unroll
        for (int r = 0; r < 4; ++r)
          of[(size_t)(mb + r) * 1024 + n] = acc[i][j][r] + bv;
      }
    }
  }
}

// ---------------- causal flash attention, swapped-QK^T, 4-way KV split ----------------
// 2048 blocks x 256 thr. Block = (bh = bid&31 [XCD-pinned], qt = bid>>5, 0..63).
// One 32-row q-tile per block; its T = qt/2+1 KV tiles split contiguously over
// the 4 waves (intra-block imbalance <= 1 iter). Partials merge via a 2-round
// LDS flash-combine tree. Inter-block imbalance absorbed by 8 blocks/CU backlog.
__global__ __launch_bounds__(256, 2) void k_attn(const u16* __restrict__ Q,
                                                 const u16* __restrict__ Kp,
                                                 const u16* __restrict__ VT,
                                                 u16* __restrict__ AO) {
  __shared__ float Osl[2][32][64];
  __shared__ float Msl[2][64];
  __shared__ float Lsl[2][64];

  const int tid = threadIdx.x;
  const int lane = tid & 63, w = tid >> 6;
  const int l31 = lane & 31, hi = lane >> 5;
  const int bh = blockIdx.x & 31;          // bh%8 == bid%8 -> bh pinned per-XCD
  const int qt = blockIdx.x >> 5;          // 0..63
  const int b = bh >> 4, h = bh & 15;
  const size_t hb = (size_t)bh * (2048 * 64);

  const int qb = qt * 32;
  const int T = (qt >> 1) + 1;             // # of 64-wide KV tiles
  const int lo  = (w * T) >> 2;            // this wave's KV chunk
  const int hiB = ((w + 1) * T) >> 2;
  const int jtmax = T - 1;                 // diagonal tile index

  const u16* Kbase = Kp + hb + (size_t)l31 * 64 + hi * 8;
  const u16* Vbase = VT + hb + (size_t)l31 * 2048 + hi * 8;
  const u16* Qbase = Q  + hb + (size_t)l31 * 64 + hi * 8;

  const bf16x8 qf0 = *(const bf16x8*)(Qbase + (size_t)qb * 64);
  const bf16x8 qf1 = *(const bf16x8*)(Qbase + (size_t)qb * 64 + 16);
  const bf16x8 qf2 = *(const bf16x8*)(Qbase + (size_t)qb * 64 + 32);
  const bf16x8 qf3 = *(const bf16x8*)(Qbase + (size_t)qb * 64 + 48);

  f32x16 o0 = (f32x16)0.0f, o1 = (f32x16)0.0f;
  float mrun = -1e30f, lrun = 0.0f;

  bf16x8 kf[2][4];
#pragma unroll
  for (int ss = 0; ss < 2; ++ss)
#pragma unroll
    for (int c = 0; c < 4; ++c)
      kf[ss][c] = *(const bf16x8*)(Kbase + (size_t)(lo * 64 + ss * 32) * 64 + c * 16);

  for (int jt = lo; jt < hiB; ++jt) {
    // V^T fragments for this KV tile (used at the end -> latency hidden)
    bf16x8 vf[2][4];
#pragma unroll
    for (int mt = 0; mt < 2; ++mt)
#pragma unroll
      for (int c = 0; c < 4; ++c)
        vf[mt][c] = *(const bf16x8*)(Vbase + (size_t)(mt * 32) * 2048 + jt * 64 + c * 16);

    // S^T[kpos][q] = K . Q^T
    f32x16 s0 = (f32x16)0.0f, s1 = (f32x16)0.0f;
    s0 = __builtin_amdgcn_mfma_f32_32x32x16_bf16(kf[0][0], qf0, s0, 0, 0, 0);
    s1 = __builtin_amdgcn_mfma_f32_32x32x16_bf16(kf[1][0], qf0, s1, 0, 0, 0);
    s0 = __builtin_amdgcn_mfma_f32_32x32x16_bf16(kf[0][1], qf1, s0, 0, 0, 0);
    s1 = __builtin_amdgcn_mfma_f32_32x32x16_bf16(kf[1][1], qf1, s1, 0, 0, 0);
    s0 = __builtin_amdgcn_mfma_f32_32x32x16_bf16(kf[0][2], qf2, s0, 0, 0, 0);
    s1 = __builtin_amdgcn_mfma_f32_32x32x16_bf16(kf[1][2], qf2, s1, 0, 0, 0);
    s0 = __builtin_amdgcn_mfma_f32_32x32x16_bf16(kf[0][3], qf3, s0, 0, 0, 0);
    s1 = __builtin_amdgcn_mfma_f32_32x32x16_bf16(kf[1][3], qf3, s1, 0, 0, 0);

    // prefetch next K tile under the softmax
    if (jt + 1 < hiB) {
#pragma unroll
      for (int ss = 0; ss < 2; ++ss)
#pragma unroll
        for (int c = 0; c < 4; ++c)
          kf[ss][c] = *(const bf16x8*)(Kbase + (size_t)((jt + 1) * 64 + ss * 32) * 64 + c * 16);
    }

    // causal mask (only the diagonal tile)
    if (jt == jtmax) {
      const int qrel = l31 + (qb - jtmax * 64);  // 0..31 (qt even) or 32..63 (qt odd)
      const int h4 = hi * 4;
#pragma unroll
      for (int r = 0; r < 16; ++r) {
        const int kp = (r & 3) + ((r >> 2) << 3) + h4;
        s0[r] = (kp <= qrel) ? s0[r] : -1e30f;
        s1[r] = (kp + 32 <= qrel) ? s1[r] : -1e30f;
      }
    }

    // ---- in-register online softmax (per lane-pair = one q-row's 32 kpos) ----
    float t8[8];
#pragma unroll
    for (int r = 0; r < 8; ++r)
      t8[r] = fmaxf(fmaxf(s0[r], s0[r + 8]), fmaxf(s1[r], s1[r + 8]));
    float tm = fmaxf(fmaxf(fmaxf(t8[0], t8[1]), fmaxf(t8[2], t8[3])),
                     fmaxf(fmaxf(t8[4], t8[5]), fmaxf(t8[6], t8[7])));
    tm = fmaxf(tm, __shfl_xor(tm, 32));
    if (!__all(tm <= mrun)) {
      const float mnew = fmaxf(mrun, tm);
      const float al = fast_exp2((mrun - mnew) * SC);
      mrun = mnew;
      lrun *= al;
#pragma unroll
      for (int r = 0; r < 16; ++r) { o0[r] *= al; o1[r] *= al; }
    }
    const float nb = -mrun * SC;
#pragma unroll
    for (int r = 0; r < 16; ++r) {
      s0[r] = fast_exp2(fmaf(s0[r], SC, nb));
      s1[r] = fast_exp2(fmaf(s1[r], SC, nb));
    }
    float u8[8];
#pragma unroll
    for (int r = 0; r < 8; ++r)
      u8[r] = (s0[r] + s0[r + 8]) + (s1[r] + s1[r + 8]);
    lrun += ((u8[0] + u8[1]) + (u8[2] + u8[3])) + ((u8[4] + u8[5]) + (u8[6] + u8[7]));

    // ---- pack P to bf16 B-fragments (cvt_pk + permlane32_swap, T12) ----
    bf16x8 pb0, pb1, pb2, pb3;
#define PACK_CHUNK(sv, bb, dst)                                   \
    {                                                             \
      u32 a0 = cvtpk(sv[bb + 0], sv[bb + 1]);                     \
      u32 a1 = cvtpk(sv[bb + 2], sv[bb + 3]);                     \
      u32 a2 = cvtpk(sv[bb + 4], sv[bb + 5]);                     \
      u32 a3 = cvtpk(sv[bb + 6], sv[bb + 7]);                     \
      plswap(a0, a2);                                             \
      plswap(a1, a3);                                             \
      u32x4 fv = {a0, a1, a2, a3};                                \
      dst = __builtin_bit_cast(bf16x8, fv);                       \
    }
    PACK_CHUNK(s0, 0, pb0)
    PACK_CHUNK(s0, 8, pb1)
    PACK_CHUNK(s1, 0, pb2)
    PACK_CHUNK(s1, 8, pb3)
#undef PACK_CHUNK

    // ---- O^T[d][q] += V^T . P^T ----
    o0 = __builtin_amdgcn_mfma_f32_32x32x16_bf16(vf[0][0], pb0, o0, 0, 0, 0);
    o1 = __builtin_amdgcn_mfma_f32_32x32x16_bf16(vf[1][0], pb0, o1, 0, 0, 0);
    o0 = __builtin_amdgcn_mfma_f32_32x32x16_bf16(vf[0][1], pb1, o0, 0, 0, 0);
    o1 = __builtin_amdgcn_mfma_f32_32x32x16_bf16(vf[1][1], pb1, o1, 0, 0, 0);
    o0 = __builtin_amdgcn_mfma_f32_32x32x16_bf16(vf[0][2], pb2, o0, 0, 0, 0);
    o1 = __builtin_amdgcn_mfma_f32_32x32x16_bf16(vf[1][2], pb2, o1, 0, 0, 0);
    o0 = __builtin_amdgcn_mfma_f32_32x32x16_bf16(vf[0][3], pb3, o0, 0, 0, 0);
    o1 = __builtin_amdgcn_mfma_f32_32x32x16_bf16(vf[1][3], pb3, o1, 0, 0, 0);
  }

  // ---- 2-round cross-wave flash combine ----
  // Round A: waves 1,3 publish; waves 0,2 absorb. Round B: wave 2 publishes; wave 0 absorbs.
  if (w & 1) {
    const int ti = w >> 1;
#pragma unroll
    for (int r = 0; r < 16; ++r) {
      Osl[ti][r][lane]      = o0[r];
      Osl[ti][16 + r][lane] = o1[r];
    }
    Msl[ti][lane] = mrun;
    Lsl[ti][lane] = lrun;
  }
  __syncthreads();
  if (!(w & 1)) {
    const int ti = w >> 1;
    const float mB = Msl[ti][lane];
    const float lB = Lsl[ti][lane];
    const float m  = fmaxf(mrun, mB);
    const float al = fast_exp2((mrun - m) * SC);
    const float bt = fast_exp2((mB - m) * SC);
    mrun = m;
    lrun = lrun * al + lB * bt;
#pragma unroll
    for (int r = 0; r < 16; ++r) {
      o0[r] = o0[r] * al + Osl[ti][r][lane] * bt;
      o1[r] = o1[r] * al + Osl[ti][16 + r][lane] * bt;
    }
  }
  if (w == 2) {
#pragma unroll
    for (int r = 0; r < 16; ++r) {
      Osl[1][r][lane]      = o0[r];
      Osl[1][16 + r][lane] = o1[r];
    }
    Msl[1][lane] = mrun;
    Lsl[1][lane] = lrun;
  }
  __syncthreads();
  if (w != 0) return;

  {
    const float mB = Msl[1][lane];
    const float lB = Lsl[1][lane];
    const float m  = fmaxf(mrun, mB);
    const float al = fast_exp2((mrun - m) * SC);
    const float bt = fast_exp2((mB - m) * SC);
    lrun = lrun * al + lB * bt;
#pragma unroll
    for (int r = 0; r < 16; ++r) {
      o0[r] = o0[r] * al + Osl[1][r][lane] * bt;
      o1[r] = o1[r] * al + Osl[1][16 + r][lane] * bt;
    }
  }

  // ---- epilogue: combine partner row-sums, normalize, store bf16 ----
  const float lt = lrun + __shfl_xor(lrun, 32);
  const float inv = 1.0f / lt;
  u16* aorow = AO + (size_t)(b * 2048 + qb + l31) * 1024 + h * 64 + hi * 4;
#pragma unroll
  for (int g = 0; g < 4; ++g) {
    u32 w0 = cvtpk(o0[4 * g + 0] * inv, o0[4 * g + 1] * inv);
    u32 w1 = cvtpk(o0[4 * g + 2] * inv, o0[4 * g + 3] * inv);
    u32x2 ww = {w0, w1};
    *(u32x2*)(aorow + g * 8) = ww;
  }
#pragma unroll
  for (int g = 0; g < 4; ++g) {
    u32 w0 = cvtpk(o1[4 * g + 0] * inv, o1[4 * g + 1] * inv);
    u32 w1 = cvtpk(o1[4 * g + 2] * inv, o1[4 * g + 3] * inv);
    u32x2 ww = {w0, w1};
    *(u32x2*)(aorow + 32 + g * 8) = ww;
  }
}

extern "C" void kernel_launch(void* const* d_in, const int* in_sizes, int n_in,
                              void* d_out, int out_size, void* d_ws, size_t ws_size,
                              hipStream_t stream) {
  const float* x      = (const float*)d_in[0];
  const float* w_attn = (const float*)d_in[1];
  const float* b_attn = (const float*)d_in[2];
  const float* w_proj = (const float*)d_in[3];
  const float* b_proj = (const float*)d_in[4];
  float* out = (float*)d_out;

  char* ws = (char*)d_ws;
  u16* x_bf  = (u16*)(ws);                    // [4096][1024] bf16   (8 MB)
  u16* wat_t = (u16*)(ws + 8388608);          // [3072][1024] bf16   (6 MB)
  u16* wpj_t = (u16*)(ws + 14680064);         // [1024][1024] bf16   (2 MB)
  u16* q_ws  = (u16*)(ws + 16777216);         // [B,H,S,d] bf16      (8 MB)
  u16* k_ws  = (u16*)(ws + 25165824);         // [B,H,S,d] bf16      (8 MB)
  u16* vT_ws = (u16*)(ws + 33554432);         // [B,H,d,S] bf16      (8 MB)
  u16* a_ws  = (u16*)(ws + 41943040);         // [B,S,nx]  bf16      (8 MB)

  k_cvt<<<4096, 256, 0, stream>>>(x, x_bf, 4194304);
  k_tcvt<<<dim3(96, 32), dim3(32, 8), 0, stream>>>(w_attn, wat_t, 1024, 3072);
  k_tcvt<<<dim3(32, 32), dim3(32, 8), 0, stream>>>(w_proj, wpj_t, 1024, 1024);

  k_gemm<0><<<dim3(24, 32), 256, 0, stream>>>(x_bf, wat_t, b_attn,
                                              q_ws, k_ws, vT_ws,
                                              out + 4194304, out + 8388608, nullptr);

  k_attn<<<dim3(2048), 256, 0, stream>>>(q_ws, k_ws, vT_ws, a_ws);

  k_gemm<1><<<dim3(8, 32), 256, 0, stream>>>(a_ws, wpj_t, b_proj,
                                             nullptr, nullptr, nullptr,
                                             nullptr, nullptr, out);
}

// Round 6
// 150.153 us; speedup vs baseline: 1.5474x; 1.0258x over previous
//
#include <hip/hip_runtime.h>
#include <stdint.h>
#include <stddef.h>

#define DEVI __device__ __forceinline__

typedef __bf16 bf16x8 __attribute__((ext_vector_type(8)));
typedef float  f32x4  __attribute__((ext_vector_type(4)));
typedef float  f32x16 __attribute__((ext_vector_type(16)));
typedef unsigned short u16;
typedef uint32_t u32;
typedef u16 u16x8 __attribute__((ext_vector_type(8)));
typedef u16 u16x4 __attribute__((ext_vector_type(4)));
typedef u32 u32x2 __attribute__((ext_vector_type(2)));
typedef u32 u32x4 __attribute__((ext_vector_type(4)));

typedef __attribute__((address_space(1))) void as1_void;
typedef __attribute__((address_space(3))) void as3_void;

static constexpr float SC = 0.18033688011112042f;  // (1/8) * log2(e)

DEVI u16 f2bf(float f) {
  uint32_t u = __builtin_bit_cast(uint32_t, f);
  u += 0x7fffu + ((u >> 16) & 1u);
  return (u16)(u >> 16);
}

DEVI void gload_lds16(const void* g, void* l) {
  __builtin_amdgcn_global_load_lds((as1_void*)(void*)g, (as3_void*)l, 16, 0, 0);
}

#if __has_builtin(__builtin_amdgcn_exp2f)
DEVI float fast_exp2(float x) { return __builtin_amdgcn_exp2f(x); }
#else
DEVI float fast_exp2(float x) { return exp2f(x); }
#endif

DEVI u32 cvtpk(float lo, float hi) {
  u32 r;
  asm("v_cvt_pk_bf16_f32 %0, %1, %2" : "=v"(r) : "v"(lo), "v"(hi));
  return r;
}
DEVI void plswap(u32& a, u32& b) {
  asm("v_permlane32_swap_b32 %0, %1" : "+v"(a), "+v"(b));
}

// ---------------- elementwise fp32 -> bf16 ----------------
__global__ __launch_bounds__(256) void k_cvt(const float* __restrict__ in,
                                             u16* __restrict__ out, int n) {
  int i = (blockIdx.x * 256 + threadIdx.x) * 4;
  if (i >= n) return;
  const float4 v = *(const float4*)(in + i);
  u16x4 o = { f2bf(v.x), f2bf(v.y), f2bf(v.z), f2bf(v.w) };
  *(u16x4*)(out + i) = o;
}

// ------------- transpose + convert: in fp32 [R][C] -> out bf16 [C][R] -------------
__global__ __launch_bounds__(256) void k_tcvt(const float* __restrict__ in,
                                              u16* __restrict__ out, int R, int C) {
  __shared__ float tile[32][33];
  const int c0 = blockIdx.x * 32, r0 = blockIdx.y * 32;
  const int tx = threadIdx.x, ty = threadIdx.y;
#pragma unroll
  for (int i = ty; i < 32; i += 8)
    tile[i][tx] = in[(size_t)(r0 + i) * C + (c0 + tx)];
  __syncthreads();
#pragma unroll
  for (int i = ty; i < 32; i += 8)
    out[(size_t)(c0 + i) * R + (r0 + tx)] = f2bf(tile[tx][i]);
}

// ---------------- GEMM: C[M][N] = A[M][K] * Bt[N][K]^T  (bf16 in, fp32 acc) ----------------
// 2-phase double-buffered staging (STAGE next tile before computing current).
// EPI 0: qkv epilogue (q,k bf16 [B,H,S,d]; v -> vT bf16 [B,H,d,S]; present fp32)
// EPI 1: proj epilogue (fp32 out + bias)
template <int EPI>
__global__ __launch_bounds__(256) void k_gemm(
    const u16* __restrict__ A, const u16* __restrict__ Bt,
    const float* __restrict__ bias,
    u16* __restrict__ wq, u16* __restrict__ wk, u16* __restrict__ vt,
    float* __restrict__ pk, float* __restrict__ pv, float* __restrict__ of) {
  constexpr int K = 1024;
  __shared__ __align__(16) u16 Ash[2][128 * 32];
  __shared__ __align__(16) u16 Bsh[2][128 * 32];
  const int tid = threadIdx.x;
  const int lane = tid & 63, wid = tid >> 6;
  const int wm = wid >> 1, wn = wid & 1;
  const int lr = lane & 15, lg = lane >> 4;
  const int m0 = blockIdx.y * 128, n0 = blockIdx.x * 128;

  const int c = wid * 64 + lane;  // 16B chunk id, 0..255
  const u16* Ag1 = A + (size_t)(m0 + (c >> 2)) * K + (c & 3) * 8;
  const u16* Ag2 = A + (size_t)(m0 + 64 + (c >> 2)) * K + (c & 3) * 8;
  const u16* Bg1 = Bt + (size_t)(n0 + (c >> 2)) * K + (c & 3) * 8;
  const u16* Bg2 = Bt + (size_t)(n0 + 64 + (c >> 2)) * K + (c & 3) * 8;

  f32x4 acc[4][4];
#pragma unroll
  for (int i = 0; i < 4; ++i)
#pragma unroll
    for (int j = 0; j < 4; ++j) acc[i][j] = (f32x4)0.0f;

#define STAGE(sel, kk)                                        \
  {                                                           \
    gload_lds16(Ag1 + (kk), &Ash[sel][wid * 512]);            \
    gload_lds16(Ag2 + (kk), &Ash[sel][2048 + wid * 512]);     \
    gload_lds16(Bg1 + (kk), &Bsh[sel][wid * 512]);            \
    gload_lds16(Bg2 + (kk), &Bsh[sel][2048 + wid * 512]);     \
  }

  STAGE(0, 0)
  __syncthreads();
  int cur = 0;
  for (int k0 = 0; k0 < K; k0 += 32) {
    if (k0 + 32 < K) STAGE(cur ^ 1, k0 + 32)
    bf16x8 af[4], bfr[4];
#pragma unroll
    for (int f = 0; f < 4; ++f) {
      af[f]  = *(const bf16x8*)&Ash[cur][(wm * 64 + f * 16 + lr) * 32 + lg * 8];
      bfr[f] = *(const bf16x8*)&Bsh[cur][(wn * 64 + f * 16 + lr) * 32 + lg * 8];
    }
#pragma unroll
    for (int i = 0; i < 4; ++i)
#pragma unroll
      for (int j = 0; j < 4; ++j)
        acc[i][j] = __builtin_amdgcn_mfma_f32_16x16x32_bf16(af[i], bfr[j], acc[i][j], 0, 0, 0);
    __syncthreads();  // drains next-tile loads (vmcnt0) + protects buffer reuse
    cur ^= 1;
  }
#undef STAGE

  if constexpr (EPI == 0) {
#pragma unroll
    for (int j = 0; j < 4; ++j) {
      const int n = n0 + wn * 64 + j * 16 + lr;
      const float bv = bias[n];
      const int sec = n >> 10;
      const int nn = n & 1023;
      const int h = nn >> 6, dd = nn & 63;
#pragma unroll
      for (int i = 0; i < 4; ++i) {
        const int mb = m0 + wm * 64 + i * 16 + lg * 4;
        const int bb = mb >> 11, ss = mb & 2047;
        const size_t ib = (size_t)(bb * 16 + h) * 131072 + (size_t)ss * 64 + dd;
        if (sec == 0) {
#pragma unroll
          for (int r = 0; r < 4; ++r)
            wq[ib + (size_t)r * 64] = f2bf(acc[i][j][r] + bv);
        } else if (sec == 1) {
#pragma unroll
          for (int r = 0; r < 4; ++r) {
            const float v = acc[i][j][r] + bv;
            wk[ib + (size_t)r * 64] = f2bf(v);
            pk[ib + (size_t)r * 64] = v;
          }
        } else {
          u16x4 vv;
#pragma unroll
          for (int r = 0; r < 4; ++r) {
            const float v = acc[i][j][r] + bv;
            pv[ib + (size_t)r * 64] = v;
            vv[r] = f2bf(v);
          }
          *(u16x4*)(vt + ((size_t)(bb * 16 + h) * 64 + dd) * 2048 + ss) = vv;
        }
      }
    }
  } else {
#pragma unroll
    for (int j = 0; j < 4; ++j) {
      const int n = n0 + wn * 64 + j * 16 + lr;
      const float bv = bias[n];
#pragma unroll
      for (int i = 0; i < 4; ++i) {
        const int mb = m0 + wm * 64 + i * 16 + lg * 4;
#pragma unroll
        for (int r = 0; r < 4; ++r)
          of[(size_t)(mb + r) * 1024 + n] = acc[i][j][r] + bv;
      }
    }
  }
}

// ---------------- causal flash attention, swapped-QK^T, paired + 4-way KV split ----------------
// 1024 blocks x 256 thr. Block = (bh = bid&31 [XCD-pinned], pair = bid>>5, 0..31).
// The block processes q-tiles `pair` then `63-pair` SEQUENTIALLY; per tile its
// T = qt/2+1 KV tiles are split over the 4 waves, partials merged via a 2-round
// LDS flash-combine. T1+T2 = 33/34 -> UNIFORM work per block (no tail).
__global__ __launch_bounds__(256, 2) void k_attn(const u16* __restrict__ Q,
                                                 const u16* __restrict__ Kp,
                                                 const u16* __restrict__ VT,
                                                 u16* __restrict__ AO) {
  __shared__ float Osl[2][32][64];
  __shared__ float Msl[2][64];
  __shared__ float Lsl[2][64];

  const int tid = threadIdx.x;
  const int lane = tid & 63, w = tid >> 6;
  const int l31 = lane & 31, hi = lane >> 5;
  const int bh = blockIdx.x & 31;          // bh%8 == bid%8 -> bh pinned per-XCD
  const int pair = blockIdx.x >> 5;        // 0..31
  const int b = bh >> 4, h = bh & 15;
  const size_t hb = (size_t)bh * (2048 * 64);

  const u16* Kbase = Kp + hb + (size_t)l31 * 64 + hi * 8;
  const u16* Vbase = VT + hb + (size_t)l31 * 2048 + hi * 8;
  const u16* Qbase = Q  + hb + (size_t)l31 * 64 + hi * 8;

  for (int t = 0; t < 2; ++t) {
    const int qt = t ? (63 - pair) : pair;
    const int qb = qt * 32;
    const int T = (qt >> 1) + 1;           // # of 64-wide KV tiles
    const int lo  = (w * T) >> 2;          // this wave's KV chunk
    const int hiB = ((w + 1) * T) >> 2;
    const int jtmax = T - 1;               // diagonal tile index

    const bf16x8 qf0 = *(const bf16x8*)(Qbase + (size_t)qb * 64);
    const bf16x8 qf1 = *(const bf16x8*)(Qbase + (size_t)qb * 64 + 16);
    const bf16x8 qf2 = *(const bf16x8*)(Qbase + (size_t)qb * 64 + 32);
    const bf16x8 qf3 = *(const bf16x8*)(Qbase + (size_t)qb * 64 + 48);

    f32x16 o0 = (f32x16)0.0f, o1 = (f32x16)0.0f;
    float mrun = -1e30f, lrun = 0.0f;

    bf16x8 kf[2][4];
#pragma unroll
    for (int ss = 0; ss < 2; ++ss)
#pragma unroll
      for (int c = 0; c < 4; ++c)
        kf[ss][c] = *(const bf16x8*)(Kbase + (size_t)(lo * 64 + ss * 32) * 64 + c * 16);

    for (int jt = lo; jt < hiB; ++jt) {
      // V^T fragments for this KV tile (used at the end -> latency hidden)
      bf16x8 vf[2][4];
#pragma unroll
      for (int mt = 0; mt < 2; ++mt)
#pragma unroll
        for (int c = 0; c < 4; ++c)
          vf[mt][c] = *(const bf16x8*)(Vbase + (size_t)(mt * 32) * 2048 + jt * 64 + c * 16);

      // S^T[kpos][q] = K . Q^T
      f32x16 s0 = (f32x16)0.0f, s1 = (f32x16)0.0f;
      s0 = __builtin_amdgcn_mfma_f32_32x32x16_bf16(kf[0][0], qf0, s0, 0, 0, 0);
      s1 = __builtin_amdgcn_mfma_f32_32x32x16_bf16(kf[1][0], qf0, s1, 0, 0, 0);
      s0 = __builtin_amdgcn_mfma_f32_32x32x16_bf16(kf[0][1], qf1, s0, 0, 0, 0);
      s1 = __builtin_amdgcn_mfma_f32_32x32x16_bf16(kf[1][1], qf1, s1, 0, 0, 0);
      s0 = __builtin_amdgcn_mfma_f32_32x32x16_bf16(kf[0][2], qf2, s0, 0, 0, 0);
      s1 = __builtin_amdgcn_mfma_f32_32x32x16_bf16(kf[1][2], qf2, s1, 0, 0, 0);
      s0 = __builtin_amdgcn_mfma_f32_32x32x16_bf16(kf[0][3], qf3, s0, 0, 0, 0);
      s1 = __builtin_amdgcn_mfma_f32_32x32x16_bf16(kf[1][3], qf3, s1, 0, 0, 0);

      // prefetch next K tile under the softmax
      if (jt + 1 < hiB) {
#pragma unroll
        for (int ss = 0; ss < 2; ++ss)
#pragma unroll
          for (int c = 0; c < 4; ++c)
            kf[ss][c] = *(const bf16x8*)(Kbase + (size_t)((jt + 1) * 64 + ss * 32) * 64 + c * 16);
      }

      // causal mask (only the diagonal tile)
      if (jt == jtmax) {
        const int qrel = l31 + (qb - jtmax * 64);  // 0..31 (qt even) or 32..63 (qt odd)
        const int h4 = hi * 4;
#pragma unroll
        for (int r = 0; r < 16; ++r) {
          const int kp = (r & 3) + ((r >> 2) << 3) + h4;
          s0[r] = (kp <= qrel) ? s0[r] : -1e30f;
          s1[r] = (kp + 32 <= qrel) ? s1[r] : -1e30f;
        }
      }

      // ---- in-register online softmax (lane pair (l31,hi) = one q-row) ----
      float t8[8];
#pragma unroll
      for (int r = 0; r < 8; ++r)
        t8[r] = fmaxf(fmaxf(s0[r], s0[r + 8]), fmaxf(s1[r], s1[r + 8]));
      float tm = fmaxf(fmaxf(fmaxf(t8[0], t8[1]), fmaxf(t8[2], t8[3])),
                       fmaxf(fmaxf(t8[4], t8[5]), fmaxf(t8[6], t8[7])));
      tm = fmaxf(tm, __shfl_xor(tm, 32));
      if (!__all(tm <= mrun)) {
        const float mnew = fmaxf(mrun, tm);
        const float al = fast_exp2((mrun - mnew) * SC);
        mrun = mnew;
        lrun *= al;
#pragma unroll
        for (int r = 0; r < 16; ++r) { o0[r] *= al; o1[r] *= al; }
      }
      const float nb = -mrun * SC;
#pragma unroll
      for (int r = 0; r < 16; ++r) {
        s0[r] = fast_exp2(fmaf(s0[r], SC, nb));
        s1[r] = fast_exp2(fmaf(s1[r], SC, nb));
      }
      float u8[8];
#pragma unroll
      for (int r = 0; r < 8; ++r)
        u8[r] = (s0[r] + s0[r + 8]) + (s1[r] + s1[r + 8]);
      lrun += ((u8[0] + u8[1]) + (u8[2] + u8[3])) + ((u8[4] + u8[5]) + (u8[6] + u8[7]));

      // ---- pack P to bf16 B-fragments (cvt_pk + permlane32_swap, T12) ----
      bf16x8 pb0, pb1, pb2, pb3;
#define PACK_CHUNK(sv, bb, dst)                                   \
      {                                                           \
        u32 a0 = cvtpk(sv[bb + 0], sv[bb + 1]);                   \
        u32 a1 = cvtpk(sv[bb + 2], sv[bb + 3]);                   \
        u32 a2 = cvtpk(sv[bb + 4], sv[bb + 5]);                   \
        u32 a3 = cvtpk(sv[bb + 6], sv[bb + 7]);                   \
        plswap(a0, a2);                                           \
        plswap(a1, a3);                                           \
        u32x4 fv = {a0, a1, a2, a3};                              \
        dst = __builtin_bit_cast(bf16x8, fv);                     \
      }
      PACK_CHUNK(s0, 0, pb0)
      PACK_CHUNK(s0, 8, pb1)
      PACK_CHUNK(s1, 0, pb2)
      PACK_CHUNK(s1, 8, pb3)
#undef PACK_CHUNK

      // ---- O^T[d][q] += V^T . P^T ----
      o0 = __builtin_amdgcn_mfma_f32_32x32x16_bf16(vf[0][0], pb0, o0, 0, 0, 0);
      o1 = __builtin_amdgcn_mfma_f32_32x32x16_bf16(vf[1][0], pb0, o1, 0, 0, 0);
      o0 = __builtin_amdgcn_mfma_f32_32x32x16_bf16(vf[0][1], pb1, o0, 0, 0, 0);
      o1 = __builtin_amdgcn_mfma_f32_32x32x16_bf16(vf[1][1], pb1, o1, 0, 0, 0);
      o0 = __builtin_amdgcn_mfma_f32_32x32x16_bf16(vf[0][2], pb2, o0, 0, 0, 0);
      o1 = __builtin_amdgcn_mfma_f32_32x32x16_bf16(vf[1][2], pb2, o1, 0, 0, 0);
      o0 = __builtin_amdgcn_mfma_f32_32x32x16_bf16(vf[0][3], pb3, o0, 0, 0, 0);
      o1 = __builtin_amdgcn_mfma_f32_32x32x16_bf16(vf[1][3], pb3, o1, 0, 0, 0);
    }

    // ---- 2-round cross-wave flash combine (uniform barriers, no early exit) ----
    if (w & 1) {
      const int ti = w >> 1;
#pragma unroll
      for (int r = 0; r < 16; ++r) {
        Osl[ti][r][lane]      = o0[r];
        Osl[ti][16 + r][lane] = o1[r];
      }
      Msl[ti][lane] = mrun;
      Lsl[ti][lane] = lrun;
    }
    __syncthreads();
    if (!(w & 1)) {
      const int ti = w >> 1;
      const float mB = Msl[ti][lane];
      const float lB = Lsl[ti][lane];
      const float m  = fmaxf(mrun, mB);
      const float al = fast_exp2((mrun - m) * SC);
      const float bt = fast_exp2((mB - m) * SC);
      mrun = m;
      lrun = lrun * al + lB * bt;
#pragma unroll
      for (int r = 0; r < 16; ++r) {
        o0[r] = o0[r] * al + Osl[ti][r][lane] * bt;
        o1[r] = o1[r] * al + Osl[ti][16 + r][lane] * bt;
      }
    }
    __syncthreads();
    if (w == 2) {
#pragma unroll
      for (int r = 0; r < 16; ++r) {
        Osl[1][r][lane]      = o0[r];
        Osl[1][16 + r][lane] = o1[r];
      }
      Msl[1][lane] = mrun;
      Lsl[1][lane] = lrun;
    }
    __syncthreads();
    if (w == 0) {
      const float mB = Msl[1][lane];
      const float lB = Lsl[1][lane];
      const float m  = fmaxf(mrun, mB);
      const float al = fast_exp2((mrun - m) * SC);
      const float bt = fast_exp2((mB - m) * SC);
      lrun = lrun * al + lB * bt;
#pragma unroll
      for (int r = 0; r < 16; ++r) {
        o0[r] = o0[r] * al + Osl[1][r][lane] * bt;
        o1[r] = o1[r] * al + Osl[1][16 + r][lane] * bt;
      }

      // ---- epilogue: combine partner row-sums, normalize, store bf16 ----
      const float lt = lrun + __shfl_xor(lrun, 32);
      const float inv = 1.0f / lt;
      u16* aorow = AO + (size_t)(b * 2048 + qb + l31) * 1024 + h * 64 + hi * 4;
#pragma unroll
      for (int g = 0; g < 4; ++g) {
        u32 w0 = cvtpk(o0[4 * g + 0] * inv, o0[4 * g + 1] * inv);
        u32 w1 = cvtpk(o0[4 * g + 2] * inv, o0[4 * g + 3] * inv);
        u32x2 ww = {w0, w1};
        *(u32x2*)(aorow + g * 8) = ww;
      }
#pragma unroll
      for (int g = 0; g < 4; ++g) {
        u32 w0 = cvtpk(o1[4 * g + 0] * inv, o1[4 * g + 1] * inv);
        u32 w1 = cvtpk(o1[4 * g + 2] * inv, o1[4 * g + 3] * inv);
        u32x2 ww = {w0, w1};
        *(u32x2*)(aorow + 32 + g * 8) = ww;
      }
    }
    __syncthreads();  // protect LDS reuse by the next phase
  }
}

extern "C" void kernel_launch(void* const* d_in, const int* in_sizes, int n_in,
                              void* d_out, int out_size, void* d_ws, size_t ws_size,
                              hipStream_t stream) {
  const float* x      = (const float*)d_in[0];
  const float* w_attn = (const float*)d_in[1];
  const float* b_attn = (const float*)d_in[2];
  const float* w_proj = (const float*)d_in[3];
  const float* b_proj = (const float*)d_in[4];
  float* out = (float*)d_out;

  char* ws = (char*)d_ws;
  u16* x_bf  = (u16*)(ws);                    // [4096][1024] bf16   (8 MB)
  u16* wat_t = (u16*)(ws + 8388608);          // [3072][1024] bf16   (6 MB)
  u16* wpj_t = (u16*)(ws + 14680064);         // [1024][1024] bf16   (2 MB)
  u16* q_ws  = (u16*)(ws + 16777216);         // [B,H,S,d] bf16      (8 MB)
  u16* k_ws  = (u16*)(ws + 25165824);         // [B,H,S,d] bf16      (8 MB)
  u16* vT_ws = (u16*)(ws + 33554432);         // [B,H,d,S] bf16      (8 MB)
  u16* a_ws  = (u16*)(ws + 41943040);         // [B,S,nx]  bf16      (8 MB)

  k_cvt<<<4096, 256, 0, stream>>>(x, x_bf, 4194304);
  k_tcvt<<<dim3(96, 32), dim3(32, 8), 0, stream>>>(w_attn, wat_t, 1024, 3072);
  k_tcvt<<<dim3(32, 32), dim3(32, 8), 0, stream>>>(w_proj, wpj_t, 1024, 1024);

  k_gemm<0><<<dim3(24, 32), 256, 0, stream>>>(x_bf, wat_t, b_attn,
                                              q_ws, k_ws, vT_ws,
                                              out + 4194304, out + 8388608, nullptr);

  k_attn<<<dim3(1024), 256, 0, stream>>>(q_ws, k_ws, vT_ws, a_ws);

  k_gemm<1><<<dim3(8, 32), 256, 0, stream>>>(a_ws, wpj_t, b_proj,
                                             nullptr, nullptr, nullptr,
                                             nullptr, nullptr, out);
}

// Round 7
// 135.665 us; speedup vs baseline: 1.7126x; 1.1068x over previous
//
#include <hip/hip_runtime.h>
#include <stdint.h>
#include <stddef.h>

#define DEVI __device__ __forceinline__

typedef __bf16 bf16x8 __attribute__((ext_vector_type(8)));
typedef float  f32x4  __attribute__((ext_vector_type(4)));
typedef float  f32x16 __attribute__((ext_vector_type(16)));
typedef unsigned short u16;
typedef uint32_t u32;
typedef u16 u16x8 __attribute__((ext_vector_type(8)));
typedef u16 u16x4 __attribute__((ext_vector_type(4)));
typedef u32 u32x2 __attribute__((ext_vector_type(2)));
typedef u32 u32x4 __attribute__((ext_vector_type(4)));

typedef __attribute__((address_space(1))) void as1_void;
typedef __attribute__((address_space(3))) void as3_void;

static constexpr float SC = 0.18033688011112042f;  // (1/8) * log2(e)

DEVI u16 f2bf(float f) {
  uint32_t u = __builtin_bit_cast(uint32_t, f);
  u += 0x7fffu + ((u >> 16) & 1u);
  return (u16)(u >> 16);
}

DEVI void gload_lds16(const void* g, void* l) {
  __builtin_amdgcn_global_load_lds((as1_void*)(void*)g, (as3_void*)l, 16, 0, 0);
}

#if __has_builtin(__builtin_amdgcn_exp2f)
DEVI float fast_exp2(float x) { return __builtin_amdgcn_exp2f(x); }
#else
DEVI float fast_exp2(float x) { return exp2f(x); }
#endif

DEVI u32 cvtpk(float lo, float hi) {
  u32 r;
  asm("v_cvt_pk_bf16_f32 %0, %1, %2" : "=v"(r) : "v"(lo), "v"(hi));
  return r;
}
DEVI void plswap(u32& a, u32& b) {
  asm("v_permlane32_swap_b32 %0, %1" : "+v"(a), "+v"(b));
}

// ---------------- elementwise fp32 -> bf16 ----------------
__global__ __launch_bounds__(256) void k_cvt(const float* __restrict__ in,
                                             u16* __restrict__ out, int n) {
  int i = (blockIdx.x * 256 + threadIdx.x) * 4;
  if (i >= n) return;
  const float4 v = *(const float4*)(in + i);
  u16x4 o = { f2bf(v.x), f2bf(v.y), f2bf(v.z), f2bf(v.w) };
  *(u16x4*)(out + i) = o;
}

// ------------- transpose + convert: in fp32 [R][C] -> out bf16 [C][R] -------------
__global__ __launch_bounds__(256) void k_tcvt(const float* __restrict__ in,
                                              u16* __restrict__ out, int R, int C) {
  __shared__ float tile[32][33];
  const int c0 = blockIdx.x * 32, r0 = blockIdx.y * 32;
  const int tx = threadIdx.x, ty = threadIdx.y;
#pragma unroll
  for (int i = ty; i < 32; i += 8)
    tile[i][tx] = in[(size_t)(r0 + i) * C + (c0 + tx)];
  __syncthreads();
#pragma unroll
  for (int i = ty; i < 32; i += 8)
    out[(size_t)(c0 + i) * R + (r0 + tx)] = f2bf(tile[tx][i]);
}

// ---------------- GEMM: C[M][N] = A[M][K] * Bt[N][K]^T  (bf16 in, fp32 acc) ----------------
// 2-phase double-buffered staging (STAGE next tile before computing current).
// EPI 0: qkv epilogue (q,k bf16 [B,H,S,d]; v -> vT bf16 [B,H,d,S]; present fp32)
// EPI 1: proj epilogue (fp32 out + bias)
template <int EPI>
__global__ __launch_bounds__(256) void k_gemm(
    const u16* __restrict__ A, const u16* __restrict__ Bt,
    const float* __restrict__ bias,
    u16* __restrict__ wq, u16* __restrict__ wk, u16* __restrict__ vt,
    float* __restrict__ pk, float* __restrict__ pv, float* __restrict__ of) {
  constexpr int K = 1024;
  __shared__ __align__(16) u16 Ash[2][128 * 32];
  __shared__ __align__(16) u16 Bsh[2][128 * 32];
  const int tid = threadIdx.x;
  const int lane = tid & 63, wid = tid >> 6;
  const int wm = wid >> 1, wn = wid & 1;
  const int lr = lane & 15, lg = lane >> 4;
  const int m0 = blockIdx.y * 128, n0 = blockIdx.x * 128;

  const int c = wid * 64 + lane;  // 16B chunk id, 0..255
  const u16* Ag1 = A + (size_t)(m0 + (c >> 2)) * K + (c & 3) * 8;
  const u16* Ag2 = A + (size_t)(m0 + 64 + (c >> 2)) * K + (c & 3) * 8;
  const u16* Bg1 = Bt + (size_t)(n0 + (c >> 2)) * K + (c & 3) * 8;
  const u16* Bg2 = Bt + (size_t)(n0 + 64 + (c >> 2)) * K + (c & 3) * 8;

  f32x4 acc[4][4];
#pragma unroll
  for (int i = 0; i < 4; ++i)
#pragma unroll
    for (int j = 0; j < 4; ++j) acc[i][j] = (f32x4)0.0f;

#define STAGE(sel, kk)                                        \
  {                                                           \
    gload_lds16(Ag1 + (kk), &Ash[sel][wid * 512]);            \
    gload_lds16(Ag2 + (kk), &Ash[sel][2048 + wid * 512]);     \
    gload_lds16(Bg1 + (kk), &Bsh[sel][wid * 512]);            \
    gload_lds16(Bg2 + (kk), &Bsh[sel][2048 + wid * 512]);     \
  }

  STAGE(0, 0)
  __syncthreads();
  int cur = 0;
  for (int k0 = 0; k0 < K; k0 += 32) {
    if (k0 + 32 < K) STAGE(cur ^ 1, k0 + 32)
    bf16x8 af[4], bfr[4];
#pragma unroll
    for (int f = 0; f < 4; ++f) {
      af[f]  = *(const bf16x8*)&Ash[cur][(wm * 64 + f * 16 + lr) * 32 + lg * 8];
      bfr[f] = *(const bf16x8*)&Bsh[cur][(wn * 64 + f * 16 + lr) * 32 + lg * 8];
    }
#pragma unroll
    for (int i = 0; i < 4; ++i)
#pragma unroll
      for (int j = 0; j < 4; ++j)
        acc[i][j] = __builtin_amdgcn_mfma_f32_16x16x32_bf16(af[i], bfr[j], acc[i][j], 0, 0, 0);
    __syncthreads();  // drains next-tile loads (vmcnt0) + protects buffer reuse
    cur ^= 1;
  }
#undef STAGE

  if constexpr (EPI == 0) {
#pragma unroll
    for (int j = 0; j < 4; ++j) {
      const int n = n0 + wn * 64 + j * 16 + lr;
      const float bv = bias[n];
      const int sec = n >> 10;
      const int nn = n & 1023;
      const int h = nn >> 6, dd = nn & 63;
#pragma unroll
      for (int i = 0; i < 4; ++i) {
        const int mb = m0 + wm * 64 + i * 16 + lg * 4;
        const int bb = mb >> 11, ss = mb & 2047;
        const size_t ib = (size_t)(bb * 16 + h) * 131072 + (size_t)ss * 64 + dd;
        if (sec == 0) {
#pragma unroll
          for (int r = 0; r < 4; ++r)
            wq[ib + (size_t)r * 64] = f2bf(acc[i][j][r] + bv);
        } else if (sec == 1) {
#pragma unroll
          for (int r = 0; r < 4; ++r) {
            const float v = acc[i][j][r] + bv;
            wk[ib + (size_t)r * 64] = f2bf(v);
            pk[ib + (size_t)r * 64] = v;
          }
        } else {
          u16x4 vv;
#pragma unroll
          for (int r = 0; r < 4; ++r) {
            const float v = acc[i][j][r] + bv;
            pv[ib + (size_t)r * 64] = v;
            vv[r] = f2bf(v);
          }
          *(u16x4*)(vt + ((size_t)(bb * 16 + h) * 64 + dd) * 2048 + ss) = vv;
        }
      }
    }
  } else {
#pragma unroll
    for (int j = 0; j < 4; ++j) {
      const int n = n0 + wn * 64 + j * 16 + lr;
      const float bv = bias[n];
#pragma unroll
      for (int i = 0; i < 4; ++i) {
        const int mb = m0 + wm * 64 + i * 16 + lg * 4;
#pragma unroll
        for (int r = 0; r < 4; ++r)
          of[(size_t)(mb + r) * 1024 + n] = acc[i][j][r] + bv;
      }
    }
  }
}

// ---------------- causal flash attention: LDS-staged K/V, swapped-QK^T ----------------
// 512 blocks x 256 thr. Block = (bh = bid&31 [XCD-pinned], 128-row superblock sb).
// sb mapping pairs co-resident blocks to uniform work: {15-(bid>>5)} then {(bid-256)>>5}.
// The block's 4 waves each own 32 q-rows and share double-buffered K/V LDS tiles
// staged via global_load_lds (4 instrs/wave/iter, no VGPR round-trip).
// LDS XOR-swizzle (slot ^ row&7) applied on BOTH sides: pre-swizzled global
// source + swizzled ds_read (involution, rule #21).
__global__ __launch_bounds__(256) void k_attn(const u16* __restrict__ Q,
                                              const u16* __restrict__ Kp,
                                              const u16* __restrict__ VT,
                                              u16* __restrict__ AO) {
  __shared__ __align__(16) u16 Ksh[2][4096];  // [kpos 64][d 64], swizzled
  __shared__ __align__(16) u16 Vsh[2][4096];  // [d 64][kpos 64], swizzled

  const int tid = threadIdx.x;
  const int lane = tid & 63, w = tid >> 6;
  const int l31 = lane & 31, hi = lane >> 5;
  const int bid = blockIdx.x;
  const int bh = bid & 31;                    // bh%8 == bid%8 -> XCD-pinned
  const int sb = (bid < 256) ? (15 - (bid >> 5)) : ((bid - 256) >> 5);
  const int b = bh >> 4, h = bh & 15;
  const size_t hb = (size_t)bh * (2048 * 64);

  const int T = 2 * sb + 2;                   // KV tiles for this superblock
  const int qb = sb * 128 + w * 32;           // this wave's 32 q-rows
  const int diag = (qb + 31) >> 6;            // last KV tile this wave computes

  // staging source (pre-swizzled): lane covers (row = base + lane>>3, slot = lane&7)
  const int srow = w * 16 + (lane >> 3);
  const int sslot = (lane & 7) ^ ((lane >> 3) & 7);
  const u16* Kg = Kp + hb + (size_t)srow * 64 + sslot * 8;
  const u16* Vg = VT + hb + (size_t)srow * 2048 + sslot * 8;

#define STAGEA(sel, jt)                                                   \
  {                                                                       \
    gload_lds16(Kg + (size_t)(jt) * 4096,         &Ksh[sel][w * 1024]);   \
    gload_lds16(Kg + (size_t)(jt) * 4096 + 512,   &Ksh[sel][w * 1024 + 512]); \
    gload_lds16(Vg + (size_t)(jt) * 64,           &Vsh[sel][w * 1024]);   \
    gload_lds16(Vg + (size_t)(jt) * 64 + 16384,   &Vsh[sel][w * 1024 + 512]); \
  }

  // Q fragments (held in registers for the whole block)
  const u16* Qp = Q + hb + (size_t)(qb + l31) * 64 + hi * 8;
  const bf16x8 qf0 = *(const bf16x8*)(Qp);
  const bf16x8 qf1 = *(const bf16x8*)(Qp + 16);
  const bf16x8 qf2 = *(const bf16x8*)(Qp + 32);
  const bf16x8 qf3 = *(const bf16x8*)(Qp + 48);

  f32x16 o0 = (f32x16)0.0f, o1 = (f32x16)0.0f;
  float mrun = -1e30f, lrun = 0.0f;

  const int xr = l31 & 7;  // read-side swizzle key

  STAGEA(0, 0)
  __syncthreads();
  int sel = 0;
  for (int jt = 0; jt < T; ++jt) {
    if (jt + 1 < T) STAGEA(sel ^ 1, jt + 1)
    if (jt <= diag) {
      const u16* Kb = Ksh[sel];
      const u16* Vb = Vsh[sel];
      // K fragments: row = s*32+l31, want slot 2c+hi -> read slot ^ (row&7)
      bf16x8 kf[2][4];
#pragma unroll
      for (int s = 0; s < 2; ++s)
#pragma unroll
        for (int c = 0; c < 4; ++c)
          kf[s][c] = *(const bf16x8*)&Kb[(s * 32 + l31) * 64 + (((2 * c + hi) ^ xr) * 8)];

      // S^T[kpos][q] = K . Q^T
      f32x16 s0 = (f32x16)0.0f, s1 = (f32x16)0.0f;
      __builtin_amdgcn_s_setprio(1);
      s0 = __builtin_amdgcn_mfma_f32_32x32x16_bf16(kf[0][0], qf0, s0, 0, 0, 0);
      s1 = __builtin_amdgcn_mfma_f32_32x32x16_bf16(kf[1][0], qf0, s1, 0, 0, 0);
      s0 = __builtin_amdgcn_mfma_f32_32x32x16_bf16(kf[0][1], qf1, s0, 0, 0, 0);
      s1 = __builtin_amdgcn_mfma_f32_32x32x16_bf16(kf[1][1], qf1, s1, 0, 0, 0);
      s0 = __builtin_amdgcn_mfma_f32_32x32x16_bf16(kf[0][2], qf2, s0, 0, 0, 0);
      s1 = __builtin_amdgcn_mfma_f32_32x32x16_bf16(kf[1][2], qf2, s1, 0, 0, 0);
      s0 = __builtin_amdgcn_mfma_f32_32x32x16_bf16(kf[0][3], qf3, s0, 0, 0, 0);
      s1 = __builtin_amdgcn_mfma_f32_32x32x16_bf16(kf[1][3], qf3, s1, 0, 0, 0);
      __builtin_amdgcn_s_setprio(0);

      // causal mask (diagonal tile only)
      if (jt == diag) {
        const int qrel = qb + l31 - diag * 64;  // 0..63
        const int h4 = hi * 4;
#pragma unroll
        for (int r = 0; r < 16; ++r) {
          const int kp = (r & 3) + ((r >> 2) << 3) + h4;
          s0[r] = (kp <= qrel) ? s0[r] : -1e30f;
          s1[r] = (kp + 32 <= qrel) ? s1[r] : -1e30f;
        }
      }

      // ---- in-register online softmax (lane pair (l31,hi) = one q-row) ----
      float t8[8];
#pragma unroll
      for (int r = 0; r < 8; ++r)
        t8[r] = fmaxf(fmaxf(s0[r], s0[r + 8]), fmaxf(s1[r], s1[r + 8]));
      float tm = fmaxf(fmaxf(fmaxf(t8[0], t8[1]), fmaxf(t8[2], t8[3])),
                       fmaxf(fmaxf(t8[4], t8[5]), fmaxf(t8[6], t8[7])));
      tm = fmaxf(tm, __shfl_xor(tm, 32));
      if (!__all(tm <= mrun)) {
        const float mnew = fmaxf(mrun, tm);
        const float al = fast_exp2((mrun - mnew) * SC);
        mrun = mnew;
        lrun *= al;
#pragma unroll
        for (int r = 0; r < 16; ++r) { o0[r] *= al; o1[r] *= al; }
      }
      const float nb = -mrun * SC;
#pragma unroll
      for (int r = 0; r < 16; ++r) {
        s0[r] = fast_exp2(fmaf(s0[r], SC, nb));
        s1[r] = fast_exp2(fmaf(s1[r], SC, nb));
      }
      float u8[8];
#pragma unroll
      for (int r = 0; r < 8; ++r)
        u8[r] = (s0[r] + s0[r + 8]) + (s1[r] + s1[r + 8]);
      lrun += ((u8[0] + u8[1]) + (u8[2] + u8[3])) + ((u8[4] + u8[5]) + (u8[6] + u8[7]));

      // ---- pack P to bf16 B-fragments (cvt_pk + permlane32_swap, T12) ----
      bf16x8 pb0, pb1, pb2, pb3;
#define PACK_CHUNK(sv, bb, dst)                                   \
      {                                                           \
        u32 a0 = cvtpk(sv[bb + 0], sv[bb + 1]);                   \
        u32 a1 = cvtpk(sv[bb + 2], sv[bb + 3]);                   \
        u32 a2 = cvtpk(sv[bb + 4], sv[bb + 5]);                   \
        u32 a3 = cvtpk(sv[bb + 6], sv[bb + 7]);                   \
        plswap(a0, a2);                                           \
        plswap(a1, a3);                                           \
        u32x4 fv = {a0, a1, a2, a3};                              \
        dst = __builtin_bit_cast(bf16x8, fv);                     \
      }
      PACK_CHUNK(s0, 0, pb0)
      PACK_CHUNK(s0, 8, pb1)
      PACK_CHUNK(s1, 0, pb2)
      PACK_CHUNK(s1, 8, pb3)
#undef PACK_CHUNK

      // V^T fragments: row = mt*32+l31 (d), want slot 2c+hi -> read slot ^ (row&7)
      bf16x8 vf[2][4];
#pragma unroll
      for (int mt = 0; mt < 2; ++mt)
#pragma unroll
        for (int c = 0; c < 4; ++c)
          vf[mt][c] = *(const bf16x8*)&Vb[(mt * 32 + l31) * 64 + (((2 * c + hi) ^ xr) * 8)];

      // ---- O^T[d][q] += V^T . P^T ----
      __builtin_amdgcn_s_setprio(1);
      o0 = __builtin_amdgcn_mfma_f32_32x32x16_bf16(vf[0][0], pb0, o0, 0, 0, 0);
      o1 = __builtin_amdgcn_mfma_f32_32x32x16_bf16(vf[1][0], pb0, o1, 0, 0, 0);
      o0 = __builtin_amdgcn_mfma_f32_32x32x16_bf16(vf[0][1], pb1, o0, 0, 0, 0);
      o1 = __builtin_amdgcn_mfma_f32_32x32x16_bf16(vf[1][1], pb1, o1, 0, 0, 0);
      o0 = __builtin_amdgcn_mfma_f32_32x32x16_bf16(vf[0][2], pb2, o0, 0, 0, 0);
      o1 = __builtin_amdgcn_mfma_f32_32x32x16_bf16(vf[1][2], pb2, o1, 0, 0, 0);
      o0 = __builtin_amdgcn_mfma_f32_32x32x16_bf16(vf[0][3], pb3, o0, 0, 0, 0);
      o1 = __builtin_amdgcn_mfma_f32_32x32x16_bf16(vf[1][3], pb3, o1, 0, 0, 0);
      __builtin_amdgcn_s_setprio(0);
    }
    __syncthreads();  // drains staged loads (vmcnt0) + protects buffer reuse
    sel ^= 1;
  }
#undef STAGEA

  // ---- epilogue: combine partner row-sums, normalize, store bf16 (per wave) ----
  const float lt = lrun + __shfl_xor(lrun, 32);
  const float inv = 1.0f / lt;
  u16* aorow = AO + (size_t)(b * 2048 + qb + l31) * 1024 + h * 64 + hi * 4;
#pragma unroll
  for (int g = 0; g < 4; ++g) {
    u32 w0 = cvtpk(o0[4 * g + 0] * inv, o0[4 * g + 1] * inv);
    u32 w1 = cvtpk(o0[4 * g + 2] * inv, o0[4 * g + 3] * inv);
    u32x2 ww = {w0, w1};
    *(u32x2*)(aorow + g * 8) = ww;
  }
#pragma unroll
  for (int g = 0; g < 4; ++g) {
    u32 w0 = cvtpk(o1[4 * g + 0] * inv, o1[4 * g + 1] * inv);
    u32 w1 = cvtpk(o1[4 * g + 2] * inv, o1[4 * g + 3] * inv);
    u32x2 ww = {w0, w1};
    *(u32x2*)(aorow + 32 + g * 8) = ww;
  }
}

extern "C" void kernel_launch(void* const* d_in, const int* in_sizes, int n_in,
                              void* d_out, int out_size, void* d_ws, size_t ws_size,
                              hipStream_t stream) {
  const float* x      = (const float*)d_in[0];
  const float* w_attn = (const float*)d_in[1];
  const float* b_attn = (const float*)d_in[2];
  const float* w_proj = (const float*)d_in[3];
  const float* b_proj = (const float*)d_in[4];
  float* out = (float*)d_out;

  char* ws = (char*)d_ws;
  u16* x_bf  = (u16*)(ws);                    // [4096][1024] bf16   (8 MB)
  u16* wat_t = (u16*)(ws + 8388608);          // [3072][1024] bf16   (6 MB)
  u16* wpj_t = (u16*)(ws + 14680064);         // [1024][1024] bf16   (2 MB)
  u16* q_ws  = (u16*)(ws + 16777216);         // [B,H,S,d] bf16      (8 MB)
  u16* k_ws  = (u16*)(ws + 25165824);         // [B,H,S,d] bf16      (8 MB)
  u16* vT_ws = (u16*)(ws + 33554432);         // [B,H,d,S] bf16      (8 MB)
  u16* a_ws  = (u16*)(ws + 41943040);         // [B,S,nx]  bf16      (8 MB)

  k_cvt<<<4096, 256, 0, stream>>>(x, x_bf, 4194304);
  k_tcvt<<<dim3(96, 32), dim3(32, 8), 0, stream>>>(w_attn, wat_t, 1024, 3072);
  k_tcvt<<<dim3(32, 32), dim3(32, 8), 0, stream>>>(w_proj, wpj_t, 1024, 1024);

  k_gemm<0><<<dim3(24, 32), 256, 0, stream>>>(x_bf, wat_t, b_attn,
                                              q_ws, k_ws, vT_ws,
                                              out + 4194304, out + 8388608, nullptr);

  k_attn<<<dim3(512), 256, 0, stream>>>(q_ws, k_ws, vT_ws, a_ws);

  k_gemm<1><<<dim3(8, 32), 256, 0, stream>>>(a_ws, wpj_t, b_proj,
                                             nullptr, nullptr, nullptr,
                                             nullptr, nullptr, out);
}

// Round 8
// 131.889 us; speedup vs baseline: 1.7616x; 1.0286x over previous
//
#include <hip/hip_runtime.h>
#include <stdint.h>
#include <stddef.h>

#define DEVI __device__ __forceinline__

typedef __bf16 bf16x8 __attribute__((ext_vector_type(8)));
typedef float  f32x4  __attribute__((ext_vector_type(4)));
typedef float  f32x16 __attribute__((ext_vector_type(16)));
typedef unsigned short u16;
typedef uint32_t u32;
typedef u16 u16x8 __attribute__((ext_vector_type(8)));
typedef u16 u16x4 __attribute__((ext_vector_type(4)));
typedef u32 u32x2 __attribute__((ext_vector_type(2)));
typedef u32 u32x4 __attribute__((ext_vector_type(4)));

typedef __attribute__((address_space(1))) void as1_void;
typedef __attribute__((address_space(3))) void as3_void;

static constexpr float SC = 0.18033688011112042f;  // (1/8) * log2(e)

DEVI u16 f2bf(float f) {
  uint32_t u = __builtin_bit_cast(uint32_t, f);
  u += 0x7fffu + ((u >> 16) & 1u);
  return (u16)(u >> 16);
}

DEVI void gload_lds16(const void* g, void* l) {
  __builtin_amdgcn_global_load_lds((as1_void*)(void*)g, (as3_void*)l, 16, 0, 0);
}

#if __has_builtin(__builtin_amdgcn_exp2f)
DEVI float fast_exp2(float x) { return __builtin_amdgcn_exp2f(x); }
#else
DEVI float fast_exp2(float x) { return exp2f(x); }
#endif

DEVI u32 cvtpk(float lo, float hi) {
  u32 r;
  asm("v_cvt_pk_bf16_f32 %0, %1, %2" : "=v"(r) : "v"(lo), "v"(hi));
  return r;
}
DEVI void plswap(u32& a, u32& b) {
  asm("v_permlane32_swap_b32 %0, %1" : "+v"(a), "+v"(b));
}

// ---------------- elementwise fp32 -> bf16 ----------------
__global__ __launch_bounds__(256) void k_cvt(const float* __restrict__ in,
                                             u16* __restrict__ out, int n) {
  int i = (blockIdx.x * 256 + threadIdx.x) * 4;
  if (i >= n) return;
  const float4 v = *(const float4*)(in + i);
  u16x4 o = { f2bf(v.x), f2bf(v.y), f2bf(v.z), f2bf(v.w) };
  *(u16x4*)(out + i) = o;
}

// ------------- transpose + convert: in fp32 [R][C] -> out bf16 [C][R] -------------
__global__ __launch_bounds__(256) void k_tcvt(const float* __restrict__ in,
                                              u16* __restrict__ out, int R, int C) {
  __shared__ float tile[32][33];
  const int c0 = blockIdx.x * 32, r0 = blockIdx.y * 32;
  const int tx = threadIdx.x, ty = threadIdx.y;
#pragma unroll
  for (int i = ty; i < 32; i += 8)
    tile[i][tx] = in[(size_t)(r0 + i) * C + (c0 + tx)];
  __syncthreads();
#pragma unroll
  for (int i = ty; i < 32; i += 8)
    out[(size_t)(c0 + i) * R + (r0 + tx)] = f2bf(tile[tx][i]);
}

// ---------------- GEMM: C[M][N] = A[M][K] * Bt[N][K]^T  (bf16 in, fp32 acc) ----------------
// 2-phase double-buffered staging (STAGE next tile before computing current).
// EPI 0: qkv epilogue (q,k bf16 [B,H,S,d]; v -> vT bf16 [B,H,d,S]; present fp32)
// EPI 1: proj epilogue (fp32 out + bias)
template <int EPI>
__global__ __launch_bounds__(256) void k_gemm(
    const u16* __restrict__ A, const u16* __restrict__ Bt,
    const float* __restrict__ bias,
    u16* __restrict__ wq, u16* __restrict__ wk, u16* __restrict__ vt,
    float* __restrict__ pk, float* __restrict__ pv, float* __restrict__ of) {
  constexpr int K = 1024;
  __shared__ __align__(16) u16 Ash[2][128 * 32];
  __shared__ __align__(16) u16 Bsh[2][128 * 32];
  const int tid = threadIdx.x;
  const int lane = tid & 63, wid = tid >> 6;
  const int wm = wid >> 1, wn = wid & 1;
  const int lr = lane & 15, lg = lane >> 4;
  const int m0 = blockIdx.y * 128, n0 = blockIdx.x * 128;

  const int c = wid * 64 + lane;  // 16B chunk id, 0..255
  const u16* Ag1 = A + (size_t)(m0 + (c >> 2)) * K + (c & 3) * 8;
  const u16* Ag2 = A + (size_t)(m0 + 64 + (c >> 2)) * K + (c & 3) * 8;
  const u16* Bg1 = Bt + (size_t)(n0 + (c >> 2)) * K + (c & 3) * 8;
  const u16* Bg2 = Bt + (size_t)(n0 + 64 + (c >> 2)) * K + (c & 3) * 8;

  f32x4 acc[4][4];
#pragma unroll
  for (int i = 0; i < 4; ++i)
#pragma unroll
    for (int j = 0; j < 4; ++j) acc[i][j] = (f32x4)0.0f;

#define STAGE(sel, kk)                                        \
  {                                                           \
    gload_lds16(Ag1 + (kk), &Ash[sel][wid * 512]);            \
    gload_lds16(Ag2 + (kk), &Ash[sel][2048 + wid * 512]);     \
    gload_lds16(Bg1 + (kk), &Bsh[sel][wid * 512]);            \
    gload_lds16(Bg2 + (kk), &Bsh[sel][2048 + wid * 512]);     \
  }

  STAGE(0, 0)
  __syncthreads();
  int cur = 0;
  for (int k0 = 0; k0 < K; k0 += 32) {
    if (k0 + 32 < K) STAGE(cur ^ 1, k0 + 32)
    bf16x8 af[4], bfr[4];
#pragma unroll
    for (int f = 0; f < 4; ++f) {
      af[f]  = *(const bf16x8*)&Ash[cur][(wm * 64 + f * 16 + lr) * 32 + lg * 8];
      bfr[f] = *(const bf16x8*)&Bsh[cur][(wn * 64 + f * 16 + lr) * 32 + lg * 8];
    }
#pragma unroll
    for (int i = 0; i < 4; ++i)
#pragma unroll
      for (int j = 0; j < 4; ++j)
        acc[i][j] = __builtin_amdgcn_mfma_f32_16x16x32_bf16(af[i], bfr[j], acc[i][j], 0, 0, 0);
    __syncthreads();  // drains next-tile loads (vmcnt0) + protects buffer reuse
    cur ^= 1;
  }
#undef STAGE

  if constexpr (EPI == 0) {
#pragma unroll
    for (int j = 0; j < 4; ++j) {
      const int n = n0 + wn * 64 + j * 16 + lr;
      const float bv = bias[n];
      const int sec = n >> 10;
      const int nn = n & 1023;
      const int h = nn >> 6, dd = nn & 63;
#pragma unroll
      for (int i = 0; i < 4; ++i) {
        const int mb = m0 + wm * 64 + i * 16 + lg * 4;
        const int bb = mb >> 11, ss = mb & 2047;
        const size_t ib = (size_t)(bb * 16 + h) * 131072 + (size_t)ss * 64 + dd;
        if (sec == 0) {
#pragma unroll
          for (int r = 0; r < 4; ++r)
            wq[ib + (size_t)r * 64] = f2bf(acc[i][j][r] + bv);
        } else if (sec == 1) {
#pragma unroll
          for (int r = 0; r < 4; ++r) {
            const float v = acc[i][j][r] + bv;
            wk[ib + (size_t)r * 64] = f2bf(v);
            pk[ib + (size_t)r * 64] = v;
          }
        } else {
          u16x4 vv;
#pragma unroll
          for (int r = 0; r < 4; ++r) {
            const float v = acc[i][j][r] + bv;
            pv[ib + (size_t)r * 64] = v;
            vv[r] = f2bf(v);
          }
          *(u16x4*)(vt + ((size_t)(bb * 16 + h) * 64 + dd) * 2048 + ss) = vv;
        }
      }
    }
  } else {
#pragma unroll
    for (int j = 0; j < 4; ++j) {
      const int n = n0 + wn * 64 + j * 16 + lr;
      const float bv = bias[n];
#pragma unroll
      for (int i = 0; i < 4; ++i) {
        const int mb = m0 + wm * 64 + i * 16 + lg * 4;
#pragma unroll
        for (int r = 0; r < 4; ++r)
          of[(size_t)(mb + r) * 1024 + n] = acc[i][j][r] + bv;
      }
    }
  }
}

// ---------------- causal flash attention: LDS-staged K/V, 2-wave blocks, LPT grid ----------------
// 1024 blocks x 128 thr (2 waves). Block = (bh = bid&31 [XCD-pinned], qt = 31-(bid>>5)).
// qt mapping dispatches LONGEST blocks first (LPT); short blocks backfill the tail.
// Each wave owns 32 q-rows of the 64-row q-tile and iterates all T = qt+1 KV tiles
// from the block-shared double-buffered LDS (no cross-wave combine needed).
// 32 KB LDS/block -> 4-5 blocks/CU co-resident = 4-5 independent barrier streams.
// LDS XOR-swizzle involution (rule #21): pre-swizzled global source + swizzled read.
__global__ __launch_bounds__(128) void k_attn(const u16* __restrict__ Q,
                                              const u16* __restrict__ Kp,
                                              const u16* __restrict__ VT,
                                              u16* __restrict__ AO) {
  __shared__ __align__(16) u16 Ksh[2][4096];  // [kpos 64][d 64], swizzled
  __shared__ __align__(16) u16 Vsh[2][4096];  // [d 64][kpos 64], swizzled

  const int tid = threadIdx.x;
  const int lane = tid & 63, w = tid >> 6;    // w in {0,1}
  const int l31 = lane & 31, hi = lane >> 5;
  const int bid = blockIdx.x;
  const int bh = bid & 31;                    // bh%8 == bid%8 -> XCD-pinned
  const int qt = 31 - (bid >> 5);             // LPT: big T first
  const int b = bh >> 4, h = bh & 15;
  const size_t hb = (size_t)bh * (2048 * 64);

  const int T = qt + 1;                       // KV tiles (diag = T-1 for both waves)
  const int qb = qt * 64 + w * 32;            // this wave's 32 q-rows

  // staging source (pre-swizzled): (row & 7) == (lane>>3) regardless of chunk
  const int srow = w * 32 + (lane >> 3);
  const int sslot = (lane & 7) ^ (lane >> 3);
  const u16* Kg = Kp + hb + (size_t)srow * 64 + sslot * 8;
  const u16* Vg = VT + hb + (size_t)srow * 2048 + sslot * 8;

#define STAGEA(sel, jt)                                                       \
  {                                                                           \
    gload_lds16(Kg + (size_t)(jt) * 4096,          &Ksh[sel][w * 2048]);      \
    gload_lds16(Kg + (size_t)(jt) * 4096 + 512,    &Ksh[sel][w * 2048 + 512]);\
    gload_lds16(Kg + (size_t)(jt) * 4096 + 1024,   &Ksh[sel][w * 2048 + 1024]);\
    gload_lds16(Kg + (size_t)(jt) * 4096 + 1536,   &Ksh[sel][w * 2048 + 1536]);\
    gload_lds16(Vg + (size_t)(jt) * 64,            &Vsh[sel][w * 2048]);      \
    gload_lds16(Vg + (size_t)(jt) * 64 + 16384,    &Vsh[sel][w * 2048 + 512]);\
    gload_lds16(Vg + (size_t)(jt) * 64 + 32768,    &Vsh[sel][w * 2048 + 1024]);\
    gload_lds16(Vg + (size_t)(jt) * 64 + 49152,    &Vsh[sel][w * 2048 + 1536]);\
  }

  // Q fragments (held in registers for the whole block)
  const u16* Qp = Q + hb + (size_t)(qb + l31) * 64 + hi * 8;
  const bf16x8 qf0 = *(const bf16x8*)(Qp);
  const bf16x8 qf1 = *(const bf16x8*)(Qp + 16);
  const bf16x8 qf2 = *(const bf16x8*)(Qp + 32);
  const bf16x8 qf3 = *(const bf16x8*)(Qp + 48);

  f32x16 o0 = (f32x16)0.0f, o1 = (f32x16)0.0f;
  float mrun = -1e30f, lrun = 0.0f;

  const int xr = l31 & 7;  // read-side swizzle key

  STAGEA(0, 0)
  __syncthreads();
  int sel = 0;
  for (int jt = 0; jt < T; ++jt) {
    if (jt + 1 < T) STAGEA(sel ^ 1, jt + 1)
    const u16* Kb = Ksh[sel];
    const u16* Vb = Vsh[sel];
    // K fragments: row = s*32+l31, want slot 2c+hi -> read slot ^ (row&7)
    bf16x8 kf[2][4];
#pragma unroll
    for (int s = 0; s < 2; ++s)
#pragma unroll
      for (int c = 0; c < 4; ++c)
        kf[s][c] = *(const bf16x8*)&Kb[(s * 32 + l31) * 64 + (((2 * c + hi) ^ xr) * 8)];

    // S^T[kpos][q] = K . Q^T
    f32x16 s0 = (f32x16)0.0f, s1 = (f32x16)0.0f;
    __builtin_amdgcn_s_setprio(1);
    s0 = __builtin_amdgcn_mfma_f32_32x32x16_bf16(kf[0][0], qf0, s0, 0, 0, 0);
    s1 = __builtin_amdgcn_mfma_f32_32x32x16_bf16(kf[1][0], qf0, s1, 0, 0, 0);
    s0 = __builtin_amdgcn_mfma_f32_32x32x16_bf16(kf[0][1], qf1, s0, 0, 0, 0);
    s1 = __builtin_amdgcn_mfma_f32_32x32x16_bf16(kf[1][1], qf1, s1, 0, 0, 0);
    s0 = __builtin_amdgcn_mfma_f32_32x32x16_bf16(kf[0][2], qf2, s0, 0, 0, 0);
    s1 = __builtin_amdgcn_mfma_f32_32x32x16_bf16(kf[1][2], qf2, s1, 0, 0, 0);
    s0 = __builtin_amdgcn_mfma_f32_32x32x16_bf16(kf[0][3], qf3, s0, 0, 0, 0);
    s1 = __builtin_amdgcn_mfma_f32_32x32x16_bf16(kf[1][3], qf3, s1, 0, 0, 0);
    __builtin_amdgcn_s_setprio(0);

    // causal mask (diagonal tile only; qrel = w*32 + l31)
    if (jt == T - 1) {
      const int qrel = w * 32 + l31;
      const int h4 = hi * 4;
#pragma unroll
      for (int r = 0; r < 16; ++r) {
        const int kp = (r & 3) + ((r >> 2) << 3) + h4;
        s0[r] = (kp <= qrel) ? s0[r] : -1e30f;
        s1[r] = (kp + 32 <= qrel) ? s1[r] : -1e30f;
      }
    }

    // ---- in-register online softmax (lane pair (l31,hi) = one q-row) ----
    float t8[8];
#pragma unroll
    for (int r = 0; r < 8; ++r)
      t8[r] = fmaxf(fmaxf(s0[r], s0[r + 8]), fmaxf(s1[r], s1[r + 8]));
    float tm = fmaxf(fmaxf(fmaxf(t8[0], t8[1]), fmaxf(t8[2], t8[3])),
                     fmaxf(fmaxf(t8[4], t8[5]), fmaxf(t8[6], t8[7])));
    tm = fmaxf(tm, __shfl_xor(tm, 32));
    if (!__all(tm <= mrun)) {
      const float mnew = fmaxf(mrun, tm);
      const float al = fast_exp2((mrun - mnew) * SC);
      mrun = mnew;
      lrun *= al;
#pragma unroll
      for (int r = 0; r < 16; ++r) { o0[r] *= al; o1[r] *= al; }
    }
    const float nb = -mrun * SC;
#pragma unroll
    for (int r = 0; r < 16; ++r) {
      s0[r] = fast_exp2(fmaf(s0[r], SC, nb));
      s1[r] = fast_exp2(fmaf(s1[r], SC, nb));
    }
    float u8[8];
#pragma unroll
    for (int r = 0; r < 8; ++r)
      u8[r] = (s0[r] + s0[r + 8]) + (s1[r] + s1[r + 8]);
    lrun += ((u8[0] + u8[1]) + (u8[2] + u8[3])) + ((u8[4] + u8[5]) + (u8[6] + u8[7]));

    // ---- pack P to bf16 B-fragments (cvt_pk + permlane32_swap, T12) ----
    bf16x8 pb0, pb1, pb2, pb3;
#define PACK_CHUNK(sv, bb, dst)                                   \
    {                                                             \
      u32 a0 = cvtpk(sv[bb + 0], sv[bb + 1]);                     \
      u32 a1 = cvtpk(sv[bb + 2], sv[bb + 3]);                     \
      u32 a2 = cvtpk(sv[bb + 4], sv[bb + 5]);                     \
      u32 a3 = cvtpk(sv[bb + 6], sv[bb + 7]);                     \
      plswap(a0, a2);                                             \
      plswap(a1, a3);                                             \
      u32x4 fv = {a0, a1, a2, a3};                                \
      dst = __builtin_bit_cast(bf16x8, fv);                       \
    }
    PACK_CHUNK(s0, 0, pb0)
    PACK_CHUNK(s0, 8, pb1)
    PACK_CHUNK(s1, 0, pb2)
    PACK_CHUNK(s1, 8, pb3)
#undef PACK_CHUNK

    // V^T fragments: row = mt*32+l31 (d), want slot 2c+hi -> read slot ^ (row&7)
    bf16x8 vf[2][4];
#pragma unroll
    for (int mt = 0; mt < 2; ++mt)
#pragma unroll
      for (int c = 0; c < 4; ++c)
        vf[mt][c] = *(const bf16x8*)&Vb[(mt * 32 + l31) * 64 + (((2 * c + hi) ^ xr) * 8)];

    // ---- O^T[d][q] += V^T . P^T ----
    __builtin_amdgcn_s_setprio(1);
    o0 = __builtin_amdgcn_mfma_f32_32x32x16_bf16(vf[0][0], pb0, o0, 0, 0, 0);
    o1 = __builtin_amdgcn_mfma_f32_32x32x16_bf16(vf[1][0], pb0, o1, 0, 0, 0);
    o0 = __builtin_amdgcn_mfma_f32_32x32x16_bf16(vf[0][1], pb1, o0, 0, 0, 0);
    o1 = __builtin_amdgcn_mfma_f32_32x32x16_bf16(vf[1][1], pb1, o1, 0, 0, 0);
    o0 = __builtin_amdgcn_mfma_f32_32x32x16_bf16(vf[0][2], pb2, o0, 0, 0, 0);
    o1 = __builtin_amdgcn_mfma_f32_32x32x16_bf16(vf[1][2], pb2, o1, 0, 0, 0);
    o0 = __builtin_amdgcn_mfma_f32_32x32x16_bf16(vf[0][3], pb3, o0, 0, 0, 0);
    o1 = __builtin_amdgcn_mfma_f32_32x32x16_bf16(vf[1][3], pb3, o1, 0, 0, 0);
    __builtin_amdgcn_s_setprio(0);

    __syncthreads();  // drains staged loads (vmcnt0) + protects buffer reuse
    sel ^= 1;
  }
#undef STAGEA

  // ---- epilogue: combine partner row-sums, normalize, store bf16 (per wave) ----
  const float lt = lrun + __shfl_xor(lrun, 32);
  const float inv = 1.0f / lt;
  u16* aorow = AO + (size_t)(b * 2048 + qb + l31) * 1024 + h * 64 + hi * 4;
#pragma unroll
  for (int g = 0; g < 4; ++g) {
    u32 w0 = cvtpk(o0[4 * g + 0] * inv, o0[4 * g + 1] * inv);
    u32 w1 = cvtpk(o0[4 * g + 2] * inv, o0[4 * g + 3] * inv);
    u32x2 ww = {w0, w1};
    *(u32x2*)(aorow + g * 8) = ww;
  }
#pragma unroll
  for (int g = 0; g < 4; ++g) {
    u32 w0 = cvtpk(o1[4 * g + 0] * inv, o1[4 * g + 1] * inv);
    u32 w1 = cvtpk(o1[4 * g + 2] * inv, o1[4 * g + 3] * inv);
    u32x2 ww = {w0, w1};
    *(u32x2*)(aorow + 32 + g * 8) = ww;
  }
}

extern "C" void kernel_launch(void* const* d_in, const int* in_sizes, int n_in,
                              void* d_out, int out_size, void* d_ws, size_t ws_size,
                              hipStream_t stream) {
  const float* x      = (const float*)d_in[0];
  const float* w_attn = (const float*)d_in[1];
  const float* b_attn = (const float*)d_in[2];
  const float* w_proj = (const float*)d_in[3];
  const float* b_proj = (const float*)d_in[4];
  float* out = (float*)d_out;

  char* ws = (char*)d_ws;
  u16* x_bf  = (u16*)(ws);                    // [4096][1024] bf16   (8 MB)
  u16* wat_t = (u16*)(ws + 8388608);          // [3072][1024] bf16   (6 MB)
  u16* wpj_t = (u16*)(ws + 14680064);         // [1024][1024] bf16   (2 MB)
  u16* q_ws  = (u16*)(ws + 16777216);         // [B,H,S,d] bf16      (8 MB)
  u16* k_ws  = (u16*)(ws + 25165824);         // [B,H,S,d] bf16      (8 MB)
  u16* vT_ws = (u16*)(ws + 33554432);         // [B,H,d,S] bf16      (8 MB)
  u16* a_ws  = (u16*)(ws + 41943040);         // [B,S,nx]  bf16      (8 MB)

  k_cvt<<<4096, 256, 0, stream>>>(x, x_bf, 4194304);
  k_tcvt<<<dim3(96, 32), dim3(32, 8), 0, stream>>>(w_attn, wat_t, 1024, 3072);
  k_tcvt<<<dim3(32, 32), dim3(32, 8), 0, stream>>>(w_proj, wpj_t, 1024, 1024);

  k_gemm<0><<<dim3(24, 32), 256, 0, stream>>>(x_bf, wat_t, b_attn,
                                              q_ws, k_ws, vT_ws,
                                              out + 4194304, out + 8388608, nullptr);

  k_attn<<<dim3(1024), 128, 0, stream>>>(q_ws, k_ws, vT_ws, a_ws);

  k_gemm<1><<<dim3(8, 32), 256, 0, stream>>>(a_ws, wpj_t, b_proj,
                                             nullptr, nullptr, nullptr,
                                             nullptr, nullptr, out);
}